// Round 6
// baseline (449.632 us; speedup 1.0000x reference)
//
#include <hip/hip_runtime.h>

typedef unsigned short u16;
typedef __attribute__((ext_vector_type(8))) short bf16x8;
typedef __attribute__((ext_vector_type(2))) float f32x2;
typedef __attribute__((ext_vector_type(4))) float f32x4;
typedef __attribute__((ext_vector_type(16))) float f32x16;
typedef __attribute__((ext_vector_type(4))) unsigned u32x4;

#define DEV static __device__ __forceinline__

DEV u16 f2bf(float f) {
    unsigned u = __float_as_uint(f);
    u += 0x7FFFu + ((u >> 16) & 1u);
    return (u16)(u >> 16);
}

DEV float uaf(unsigned u) { return __uint_as_float(u); }

typedef const __attribute__((address_space(1))) void* gas1_t;
typedef __attribute__((address_space(3))) void* gas3_t;

DEV void gl_lds16(const u16* g, u16* l) {
    __builtin_amdgcn_global_load_lds((gas1_t)g, (gas3_t)l, 16, 0, 0);
}

DEV unsigned cvtpk_bf16(float a, float b) {
    unsigned r;
    asm("v_cvt_pk_bf16_f32 %0, %1, %2" : "=v"(r) : "v"(a), "v"(b));
    return r;
}

// swizzled LDS offset (u16 units) for 128B rows of 64 u16, 16B chunks
DEV int sw8(int row, int chunk) { return row * 64 + ((chunk ^ (row & 7)) << 3); }

// ---------------- merged prep: weight casts + bias permute + mask pack ----------------
// block ranges: [0,3072) qkvW | [3072,4096) oW | [4096,8192) p1W | [8192,12288) p2W
//               | [12288,16384) mask transpose-pack | 16384 pbias
__global__ __launch_bounds__(256) void prep_all(const float* __restrict__ qkv_w,
                                                const float* __restrict__ o_w,
                                                const float* __restrict__ p1_w,
                                                const float* __restrict__ p2_w,
                                                const float* __restrict__ qkv_b,
                                                const float* __restrict__ nm,
                                                const float* __restrict__ pm,
                                                u16* __restrict__ qkvW,
                                                u16* __restrict__ oW,
                                                u16* __restrict__ p1W,
                                                u16* __restrict__ p2W,
                                                float* __restrict__ pbias,
                                                unsigned* __restrict__ Mp) {
    __shared__ uint4 Ls[512];   // 8KB, used only by the mask branch
    const int bid = blockIdx.x, t = threadIdx.x;
    if (bid < 3072) {            // qkv cast + row permute: rows = [V|Q|K], each h*64+t
        int i = bid * 256 + t;
        int orow = i >> 8, cc = i & 255;
        int region = orow >> 10, rem = orow & 1023, h = rem >> 6, tt = rem & 63;
        int srow = h * 192 + region * 64 + tt;
        float4 v = ((const float4*)qkv_w)[srow * 256 + cc];
        ushort4 o;
        o.x = f2bf(v.x); o.y = f2bf(v.y); o.z = f2bf(v.z); o.w = f2bf(v.w);
        ((ushort4*)qkvW)[i] = o;
    } else if (bid < 4096) {     // o_w cast
        int i = (bid - 3072) * 256 + t;
        float4 v = ((const float4*)o_w)[i];
        ushort4 o;
        o.x = f2bf(v.x); o.y = f2bf(v.y); o.z = f2bf(v.z); o.w = f2bf(v.w);
        ((ushort4*)oW)[i] = o;
    } else if (bid < 8192) {     // p1_w cast
        int i = (bid - 4096) * 256 + t;
        float4 v = ((const float4*)p1_w)[i];
        ushort4 o;
        o.x = f2bf(v.x); o.y = f2bf(v.y); o.z = f2bf(v.z); o.w = f2bf(v.w);
        ((ushort4*)p1W)[i] = o;
    } else if (bid < 12288) {    // p2_w cast
        int i = (bid - 8192) * 256 + t;
        float4 v = ((const float4*)p2_w)[i];
        ushort4 o;
        o.x = f2bf(v.x); o.y = f2bf(v.y); o.z = f2bf(v.z); o.w = f2bf(v.w);
        ((ushort4*)p2W)[i] = o;
    } else if (bid < 16384) {    // mask pack: LDS-transposed, dense in and out
        // tile = one b, one mt (32 m), 64 n. layout out: [b][mt][c][n][hi] uint4
        // lo half = bf16(nm*8): attn inits the QK accumulator with 8*nm, then
        // scales by CS=0.125*log2e -> exp2((S+8nm)*CS) == exp(S/8 + nm)
        const int idx = bid - 12288;
        const int bb = idx >> 11, r2 = idx & 2047;
        const int mt = r2 >> 5, nt = r2 & 31;
        const int n0 = nt * 64;
        // read: 2 consecutive float4 (8 m) per array per thread, coalesced
        const int n = t >> 2;
        const int mq0 = (t & 3) * 2;
        const size_t fbase = (size_t)bb * 1048576 + (size_t)(n0 + n) * 512 + mt * 8 + mq0;
        const float4 a0 = ((const float4*)nm)[fbase];
        const float4 a1 = ((const float4*)nm)[fbase + 1];
        const float4 b0 = ((const float4*)pm)[fbase];
        const float4 b1 = ((const float4*)pm)[fbase + 1];
        uint4 o0, o1;
        o0.x = ((unsigned)f2bf(b0.x) << 16) | f2bf(a0.x * 8.0f);
        o0.y = ((unsigned)f2bf(b0.y) << 16) | f2bf(a0.y * 8.0f);
        o0.z = ((unsigned)f2bf(b0.z) << 16) | f2bf(a0.z * 8.0f);
        o0.w = ((unsigned)f2bf(b0.w) << 16) | f2bf(a0.w * 8.0f);
        o1.x = ((unsigned)f2bf(b1.x) << 16) | f2bf(a1.x * 8.0f);
        o1.y = ((unsigned)f2bf(b1.y) << 16) | f2bf(a1.y * 8.0f);
        o1.z = ((unsigned)f2bf(b1.z) << 16) | f2bf(a1.z * 8.0f);
        o1.w = ((unsigned)f2bf(b1.w) << 16) | f2bf(a1.w * 8.0f);
        // slot: m5 = 8c + 4hi + {0..3};  mq0 even -> (c=mq0>>1, hi=0), mq0+1 -> hi=1
        const int c = mq0 >> 1;
        Ls[c * 128 + n * 2 + 0] = o0;
        Ls[c * 128 + n * 2 + 1] = o1;
        __syncthreads();
        // write: per c, 128 consecutive uint4 (2KB) fully coalesced
        const int wc = t >> 6, j = t & 63;
        const size_t obase = (((size_t)(bb * 64 + mt) * 4) + wc) * 4096 + (size_t)n0 * 2;
        ((uint4*)Mp)[obase + j] = Ls[wc * 128 + j];
        ((uint4*)Mp)[obase + 64 + j] = Ls[wc * 128 + 64 + j];
    } else {                     // qkv bias permute (3072 elements)
#pragma unroll
        for (int k = 0; k < 12; k++) {
            int i = k * 256 + t;
            int region = i >> 10, rem = i & 1023, h = rem >> 6, tt = rem & 63;
            pbias[i] = qkv_b[h * 192 + region * 64 + tt];
        }
    }
}

// ---------------- LayerNorm (D=1024) f32 -> bf16 ----------------
__global__ __launch_bounds__(256) void ln_bf16(const float* __restrict__ x,
                                               const float* __restrict__ gam,
                                               const float* __restrict__ bet,
                                               u16* __restrict__ y) {
    const int row = blockIdx.x;
    const int t = threadIdx.x;
    const float4 v = ((const float4*)(x + (size_t)row * 1024))[t];
    float s = v.x + v.y + v.z + v.w;
    float ss = v.x * v.x + v.y * v.y + v.z * v.z + v.w * v.w;
#pragma unroll
    for (int o = 1; o < 64; o <<= 1) {
        s += __shfl_xor(s, o);
        ss += __shfl_xor(ss, o);
    }
    __shared__ float rs[4], rss[4];
    const int wave = t >> 6, lane = t & 63;
    if (lane == 0) { rs[wave] = s; rss[wave] = ss; }
    __syncthreads();
    const float tot = rs[0] + rs[1] + rs[2] + rs[3];
    const float totss = rss[0] + rss[1] + rss[2] + rss[3];
    const float mu = tot * (1.0f / 1024.0f);
    const float var = totss * (1.0f / 1024.0f) - mu * mu;
    const float rstd = rsqrtf(var + 1e-5f);
    const float4 g4 = ((const float4*)gam)[t];
    const float4 b4 = ((const float4*)bet)[t];
    ushort4 o;
    o.x = f2bf((v.x - mu) * rstd * g4.x + b4.x);
    o.y = f2bf((v.y - mu) * rstd * g4.y + b4.y);
    o.z = f2bf((v.z - mu) * rstd * g4.z + b4.z);
    o.w = f2bf((v.w - mu) * rstd * g4.w + b4.w);
    ((ushort4*)(y + (size_t)row * 1024))[t] = o;
}

// ---- fused 4-way combine + residual + LayerNorm ----
__global__ __launch_bounds__(256) void ln2_comb4(const float* __restrict__ p0,
                                                 const float* __restrict__ p1,
                                                 const float* __restrict__ p2,
                                                 const float* __restrict__ p3,
                                                 const float* __restrict__ Z,
                                                 const float* __restrict__ gam,
                                                 const float* __restrict__ bet,
                                                 float* __restrict__ Z1,
                                                 u16* __restrict__ y) {
    const int row = blockIdx.x;
    const int t = threadIdx.x;
    const size_t off = (size_t)row * 256 + t;
    const float4 a = ((const float4*)p0)[off];
    const float4 c = ((const float4*)p1)[off];
    const float4 d = ((const float4*)p2)[off];
    const float4 e = ((const float4*)p3)[off];
    const float4 z = ((const float4*)Z)[off];
    float4 v;
    v.x = a.x + c.x + d.x + e.x + z.x;
    v.y = a.y + c.y + d.y + e.y + z.y;
    v.z = a.z + c.z + d.z + e.z + z.z;
    v.w = a.w + c.w + d.w + e.w + z.w;
    ((float4*)Z1)[off] = v;
    float s = v.x + v.y + v.z + v.w;
    float ss = v.x * v.x + v.y * v.y + v.z * v.z + v.w * v.w;
#pragma unroll
    for (int o = 1; o < 64; o <<= 1) {
        s += __shfl_xor(s, o);
        ss += __shfl_xor(ss, o);
    }
    __shared__ float rs[4], rss[4];
    const int wave = t >> 6, lane = t & 63;
    if (lane == 0) { rs[wave] = s; rss[wave] = ss; }
    __syncthreads();
    const float tot = rs[0] + rs[1] + rs[2] + rs[3];
    const float totss = rss[0] + rss[1] + rss[2] + rss[3];
    const float mu = tot * (1.0f / 1024.0f);
    const float var = totss * (1.0f / 1024.0f) - mu * mu;
    const float rstd = rsqrtf(var + 1e-5f);
    const float4 g4 = ((const float4*)gam)[t];
    const float4 b4 = ((const float4*)bet)[t];
    ushort4 o;
    o.x = f2bf((v.x - mu) * rstd * g4.x + b4.x);
    o.y = f2bf((v.y - mu) * rstd * g4.y + b4.y);
    o.z = f2bf((v.z - mu) * rstd * g4.z + b4.z);
    o.w = f2bf((v.w - mu) * rstd * g4.w + b4.w);
    ((ushort4*)(y + (size_t)row * 1024))[t] = o;
}

// ---- final combine: out = p0 + p1 + bias + Z1 ----
__global__ __launch_bounds__(256) void out_comb(const float* __restrict__ p0,
                                                const float* __restrict__ p1,
                                                const float* __restrict__ bias,
                                                const float* __restrict__ Z1,
                                                float* __restrict__ out) {
    int i = blockIdx.x * 256 + threadIdx.x;   // 1048576 float4s
    float4 a = ((const float4*)p0)[i];
    float4 c = ((const float4*)p1)[i];
    float4 z = ((const float4*)Z1)[i];
    float4 b = ((const float4*)bias)[i & 255];
    float4 o;
    o.x = a.x + c.x + z.x + b.x; o.y = a.y + c.y + z.y + b.y;
    o.z = a.z + c.z + z.z + b.z; o.w = a.w + c.w + z.w + b.w;
    ((float4*)out)[i] = o;
}

// ---------------- GEMM v9: double-buffered, sw4-swizzled, XCD-chunked ----------------
// C[M,N] = A[M,K-slice] @ Bt[N,K-slice]^T. 128x128 tile, BK=32, 2 k-steps/iter.
// EPI 0: +pbias; region: 0 -> f32 Vsc(out0), 1 -> Q bf16(out1), 2 -> K bf16(out2)
// EPI 2: +bias, relu, write bf16 out0
// EPI 4: raw f32 partial -> (z<2 ? out0 : out1) + (z&1)*M*N
template <int EPI>
__global__ __launch_bounds__(256, 4) void gemm_bt(const u16* __restrict__ A,
                                                  const u16* __restrict__ Bt,
                                                  const float* __restrict__ bias,
                                                  void* __restrict__ out0,
                                                  void* __restrict__ out1,
                                                  void* __restrict__ out2,
                                                  int M, int N, int K, int ldk) {
    __shared__ __align__(16) u16 As[2][128 * 32];
    __shared__ __align__(16) u16 Bs[2][128 * 32];
    const int tid = threadIdx.x;
    const int wave = tid >> 6, lane = tid & 63;
    const int lhi = lane >> 4, llo = lane & 15;
    // XCD-chunked block swizzle (nwg_xy is a multiple of 8 for all call sites)
    const int gx = gridDim.x;
    const int bid = blockIdx.y * gx + blockIdx.x;
    const int swz = (bid & 7) * ((gx * gridDim.y) >> 3) + (bid >> 3);
    const int bx = swz % gx, by = swz / gx;
    const int kz = blockIdx.z * K;

    const int arow = wave * 32 + (lane >> 2);
    const int asw = ((lane & 3) ^ ((lane >> 2) & 3)) << 3;  // pre-swizzled source col
    const u16* gA = A + (size_t)(by * 128 + arow) * ldk + kz + asw;
    const u16* gB = Bt + (size_t)(bx * 128 + arow) * ldk + kz + asw;
    u16* lA0 = As[0] + wave * 1024 + lane * 8;
    u16* lA1 = As[1] + wave * 1024 + lane * 8;
    u16* lB0 = Bs[0] + wave * 1024 + lane * 8;
    u16* lB1 = Bs[1] + wave * 1024 + lane * 8;

#define GSTAGE(LA, LB) do { \
        gl_lds16(gA, LA); gl_lds16(gA + 16 * (size_t)ldk, (LA) + 512); \
        gl_lds16(gB, LB); gl_lds16(gB + 16 * (size_t)ldk, (LB) + 512); \
        gA += 32; gB += 32; } while (0)

    const int wr = wave >> 1, wc = wave & 1;
    const f32x4 zero = {0.f, 0.f, 0.f, 0.f};
    f32x4 acc[4][4];
#pragma unroll
    for (int i = 0; i < 4; i++)
#pragma unroll
        for (int j = 0; j < 4; j++) acc[i][j] = zero;

    // sw4 read offsets: row r, global chunk lhi lives at LDS chunk (lhi ^ (r&3))
#define GCOMP(AB, BB) do { \
        bf16x8 af[4], bfr[4]; \
        _Pragma("unroll") \
        for (int i = 0; i < 4; i++) { \
            const int r = wr * 64 + i * 16 + llo; \
            af[i] = *(const bf16x8*)((AB) + r * 32 + (((lhi ^ r) & 3) << 3)); \
        } \
        _Pragma("unroll") \
        for (int j = 0; j < 4; j++) { \
            const int r = wc * 64 + j * 16 + llo; \
            bfr[j] = *(const bf16x8*)((BB) + r * 32 + (((lhi ^ r) & 3) << 3)); \
        } \
        __builtin_amdgcn_s_setprio(1); \
        _Pragma("unroll") \
        for (int i = 0; i < 4; i++) \
            _Pragma("unroll") \
            for (int j = 0; j < 4; j++) \
                acc[i][j] = __builtin_amdgcn_mfma_f32_16x16x32_bf16(af[i], bfr[j], acc[i][j], 0, 0, 0); \
        __builtin_amdgcn_s_setprio(0); \
        __syncthreads(); } while (0)

    // 2-phase pipeline: stage(next) issued before compute(cur); 1 barrier/step
    GSTAGE(lA0, lB0);
    __syncthreads();
    for (int k0 = 0; k0 < K; k0 += 64) {
        if (k0 + 32 < K) GSTAGE(lA1, lB1);
        GCOMP(As[0], Bs[0]);
        if (k0 + 64 < K) GSTAGE(lA0, lB0);
        GCOMP(As[1], Bs[1]);
    }
#undef GCOMP
#undef GSTAGE

    const int rbase = by * 128 + wr * 64 + lhi * 4;
    const int cbase = bx * 128 + wc * 64 + llo;
    float* pout = nullptr;
    if constexpr (EPI == 4) {
        pout = (blockIdx.z < 2) ? ((float*)out0 + (size_t)blockIdx.z * M * N)
                                : ((float*)out1 + (size_t)(blockIdx.z - 2) * M * N);
    }
#pragma unroll
    for (int i = 0; i < 4; i++) {
#pragma unroll
        for (int j = 0; j < 4; j++) {
#pragma unroll
            for (int r = 0; r < 4; r++) {
                const int row = rbase + i * 16 + r;
                const int col = cbase + j * 16;
                float v = acc[i][j][r];
                if constexpr (EPI == 0) {
                    v += bias[col];
                    const int region = col >> 10;   // uniform per block
                    const int c = col & 1023;       // h*64 + t
                    const int b = row >> 11, n = row & 2047;
                    if (region == 0) {
                        ((float*)out0)[(size_t)row * 1024 + c] = v;  // Vsc f32
                    } else {
                        const int h = c >> 6, t = c & 63;
                        u16* dst = (region == 1) ? (u16*)out1 : (u16*)out2;
                        dst[(((size_t)(b * 16 + h)) * 2048 + n) * 64 + t] = f2bf(v);
                    }
                } else if constexpr (EPI == 2) {
                    v += bias[col];
                    v = v > 0.f ? v : 0.f;
                    ((u16*)out0)[(size_t)row * N + col] = f2bf(v);
                } else {
                    pout[(size_t)row * N + col] = v;
                }
            }
        }
    }
}

// ---------------- V transpose: Vsc f32 [B*N][1024] -> Vt bf16 [BH][64][2048] --
// m-columns written in PV k-order (pg permutation within each 32-m block).
__global__ __launch_bounds__(256) void vtrans(const float* __restrict__ Vsc,
                                              u16* __restrict__ Vt) {
    __shared__ u16 Ts[64 * 72];
    const int nt = blockIdx.x;  // n-tile (0..31)
    const int bh = blockIdx.y;  // 0..31
    const int b = bh >> 4, h = bh & 15;
    const int t = threadIdx.x;
    const int n0 = nt * 64;
    const int nr = t >> 2;
    const int dq = (t & 3) * 16;
    const float* src = Vsc + ((size_t)(b * 2048 + n0 + nr)) * 1024 + h * 64 + dq;
    float4 v0 = ((const float4*)src)[0];
    float4 v1 = ((const float4*)src)[1];
    float4 v2 = ((const float4*)src)[2];
    float4 v3 = ((const float4*)src)[3];
    u16* c0 = Ts + nr;
    c0[(dq + 0) * 72]  = f2bf(v0.x); c0[(dq + 1) * 72]  = f2bf(v0.y);
    c0[(dq + 2) * 72]  = f2bf(v0.z); c0[(dq + 3) * 72]  = f2bf(v0.w);
    c0[(dq + 4) * 72]  = f2bf(v1.x); c0[(dq + 5) * 72]  = f2bf(v1.y);
    c0[(dq + 6) * 72]  = f2bf(v1.z); c0[(dq + 7) * 72]  = f2bf(v1.w);
    c0[(dq + 8) * 72]  = f2bf(v2.x); c0[(dq + 9) * 72]  = f2bf(v2.y);
    c0[(dq + 10) * 72] = f2bf(v2.z); c0[(dq + 11) * 72] = f2bf(v2.w);
    c0[(dq + 12) * 72] = f2bf(v3.x); c0[(dq + 13) * 72] = f2bf(v3.y);
    c0[(dq + 14) * 72] = f2bf(v3.z); c0[(dq + 15) * 72] = f2bf(v3.w);
    __syncthreads();
    const int d = t >> 2, n8 = (t & 3) * 16;
    u16* dstrow = Vt + ((size_t)bh * 64 + d) * 2048 + n0;
#pragma unroll
    for (int w = 0; w < 4; w++) {
        const int gi = (n8 >> 2) + w;          // m-group id within 64-tile
        const int g5 = gi & 7, blk = gi >> 3;
        const int pg = (g5 & 4) | ((g5 & 1) << 1) | ((g5 >> 1) & 1);
        *(uint2*)(dstrow + blk * 32 + pg * 4) = *(const uint2*)(Ts + d * 72 + n8 + w * 4);
    }
}

// ---------------- fused flash-style attention v10 ----------------
// v8/v9 memory structure + mask-init sacc (8*nm in lo half) with one-tile-ahead
// mask register prefetch: no zero-init movs, no mask-add fma, no wait before QK.
__global__ __launch_bounds__(256, 4) void attn_fused9(const u16* __restrict__ Qg,
                                                      const u16* __restrict__ Kg,
                                                      const u16* __restrict__ Vtg,
                                                      const unsigned* __restrict__ Mp,
                                                      u16* __restrict__ attnL) {
    __shared__ __align__(16) u16 Ks[2][64 * 64];
    __shared__ __align__(16) u16 Vs[2][64 * 64];
    __shared__ float lsh[2][32], lsh2[2][32];
    const int tid = threadIdx.x, wave = tid >> 6, lane = tid & 63;
    const int qh = wave & 1, wm = wave >> 1;       // q-half, m-split
    const int hi = lane >> 5, l31 = lane & 31;
    // XCD-grouped block decode: 16 heads of a (b,qt) group on one XCD
    const int pid = blockIdx.x;
    const int seq = pid >> 3;
    const int hh = seq & 15;
    const int g = (pid & 7) + (seq >> 4) * 8;
    const int b = g >> 5, qt = g & 31;
    const int bh = b * 16 + hh;
    const int q0 = qt * 64;

    // loop-carried staging pointers
    const int l3 = lane >> 3, l7 = lane & 7;
    const int swcol = (l7 ^ l3) << 3;
    const int srow = wave * 16 + l3;
    const u16* kp = Kg + ((size_t)bh * 2048 + srow) * 64 + swcol;
    const u16* vp = Vtg + ((size_t)bh * 64 + srow) * 2048 + swcol;
    u16* lKa = Ks[0] + wave * 1024 + lane * 8;
    u16* lKb = Ks[1] + wave * 1024 + lane * 8;
    u16* lVa = Vs[0] + wave * 1024 + lane * 8;
    u16* lVb = Vs[1] + wave * 1024 + lane * 8;

#define STAGE(LK, LV) do { \
        gl_lds16(kp, LK); gl_lds16(kp + 512, (LK) + 512); \
        gl_lds16(vp, LV); gl_lds16(vp + 16384, (LV) + 512); \
        kp += 4096; vp += 64; } while (0)

    // prologue: stage tile 0, Q fragments to registers
    STAGE(lKa, lVa);
    const int qrow = q0 + qh * 32 + l31;
    const u16* qptr = Qg + ((size_t)bh * 2048 + qrow) * 64 + hi * 8;
    bf16x8 qf[4];
#pragma unroll
    for (int ks = 0; ks < 4; ks++) qf[ks] = *(const bf16x8*)(qptr + ks * 16);

    // coalesced mask base: [b][mt][c][n][hi] (uint4 units), mt = 2t + wm
    const uint4* mp = (const uint4*)Mp + (size_t)(b * 64 + wm) * 16384
                                       + (size_t)qrow * 2 + hi;
    // mask tile 0 -> registers
    uint4 mA0 = mp[0], mA1 = mp[4096], mA2 = mp[8192], mA3 = mp[12288];
    uint4 mB0, mB1, mB2, mB3;
    mp += 32768;

    const f32x16 z16 = {0.f,0.f,0.f,0.f,0.f,0.f,0.f,0.f,0.f,0.f,0.f,0.f,0.f,0.f,0.f,0.f};
    f32x16 accO[2];
    accO[0] = z16; accO[1] = z16;
    f32x2 lsv = {0.f, 0.f};
    const float CS = 0.125f * 1.4426950f;
    const f32x2 csv = {CS, CS};
    __syncthreads();

#define QUAD(M, q) { \
        const f32x2 s0 = {sacc[q] * CS, sacc[q + 1] * CS}; \
        const f32x2 s1 = {sacc[q + 2] * CS, sacc[q + 3] * CS}; \
        f32x2 e0 = {__builtin_amdgcn_exp2f(s0.x), __builtin_amdgcn_exp2f(s0.y)}; \
        f32x2 e1 = {__builtin_amdgcn_exp2f(s1.x), __builtin_amdgcn_exp2f(s1.y)}; \
        lsv += e0; lsv += e1; \
        const f32x2 pm0 = {uaf(M.x & 0xFFFF0000u), uaf(M.y & 0xFFFF0000u)}; \
        const f32x2 pm1 = {uaf(M.z & 0xFFFF0000u), uaf(M.w & 0xFFFF0000u)}; \
        e0 *= pm0; e1 *= pm1; \
        wpk[(q) / 2] = cvtpk_bf16(e0.x, e0.y); \
        wpk[(q) / 2 + 1] = cvtpk_bf16(e1.x, e1.y); }

    // ITER: prefetch NEXT masks to registers, stage NEXT K/V tile, then compute
    // current tile with sacc initialized from CURRENT masks (8*nm in lo half).
#define ITER(KSB, VSB, LK, LV, MC0, MC1, MC2, MC3, MN0, MN1, MN2, MN3, DO_PF) do { \
        if (DO_PF) { \
            MN0 = mp[0]; MN1 = mp[4096]; MN2 = mp[8192]; MN3 = mp[12288]; \
            mp += 32768; \
            STAGE(LK, LV); \
        } \
        f32x16 sacc; \
        sacc[0] = uaf(MC0.x << 16); sacc[1] = uaf(MC0.y << 16); \
        sacc[2] = uaf(MC0.z << 16); sacc[3] = uaf(MC0.w << 16); \
        sacc[4] = uaf(MC1.x << 16); sacc[5] = uaf(MC1.y << 16); \
        sacc[6] = uaf(MC1.z << 16); sacc[7] = uaf(MC1.w << 16); \
        sacc[8] = uaf(MC2.x << 16); sacc[9] = uaf(MC2.y << 16); \
        sacc[10] = uaf(MC2.z << 16); sacc[11] = uaf(MC2.w << 16); \
        sacc[12] = uaf(MC3.x << 16); sacc[13] = uaf(MC3.y << 16); \
        sacc[14] = uaf(MC3.z << 16); sacc[15] = uaf(MC3.w << 16); \
        __builtin_amdgcn_s_setprio(1); \
        _Pragma("unroll") \
        for (int ks = 0; ks < 4; ks++) { \
            const bf16x8 kf = *(const bf16x8*)((KSB) + sw8(wm * 32 + l31, ks * 2 + hi)); \
            sacc = __builtin_amdgcn_mfma_f32_32x32x16_bf16(kf, qf[ks], sacc, 0, 0, 0); \
        } \
        __builtin_amdgcn_s_setprio(0); \
        unsigned wpk[8]; \
        QUAD(MC0, 0) QUAD(MC1, 4) QUAD(MC2, 8) QUAD(MC3, 12) \
        const u32x4 fa0v = {wpk[0], wpk[1], wpk[2], wpk[3]}; \
        const u32x4 fa1v = {wpk[4], wpk[5], wpk[6], wpk[7]}; \
        const bf16x8 pa0 = __builtin_bit_cast(bf16x8, fa0v); \
        const bf16x8 pa1 = __builtin_bit_cast(bf16x8, fa1v); \
        __builtin_amdgcn_s_setprio(1); \
        _Pragma("unroll") \
        for (int dh = 0; dh < 2; dh++) { \
            const bf16x8 vf0 = *(const bf16x8*)((VSB) + sw8(dh * 32 + l31, wm * 4 + hi)); \
            accO[dh] = __builtin_amdgcn_mfma_f32_32x32x16_bf16(pa0, vf0, accO[dh], 0, 0, 0); \
            const bf16x8 vf1 = *(const bf16x8*)((VSB) + sw8(dh * 32 + l31, wm * 4 + 2 + hi)); \
            accO[dh] = __builtin_amdgcn_mfma_f32_32x32x16_bf16(pa1, vf1, accO[dh], 0, 0, 0); \
        } \
        __builtin_amdgcn_s_setprio(0); \
        __syncthreads(); } while (0)

    for (int tt = 0; tt < 16; tt++) {
        // even tile 2tt: consume mA; prefetch tile 2tt+1 (masks->mB, KV->buf1)
        ITER(Ks[0], Vs[0], lKb, lVb, mA0, mA1, mA2, mA3, mB0, mB1, mB2, mB3, true);
        // odd tile 2tt+1: consume mB; prefetch tile 2tt+2 (masks->mA, KV->buf0)
        ITER(Ks[1], Vs[1], lKa, lVa, mB0, mB1, mB2, mB3, mA0, mA1, mA2, mA3, (tt < 15));
    }
#undef ITER
#undef QUAD
#undef STAGE

    // combine the wm pair (same qh): conflict-free XOR-swizzled LDS buffer
    const float lsum = lsv.x + lsv.y;
    const float lsum2 = lsum + __shfl_xor(lsum, 32);
    float* cb = (float*)&Ks[0][0];   // 16 KB: 128 slots x 32 floats, swizzled
    const int slot = qh * 64 + lane;
    const int s7 = slot & 7;
    if (wm == 1) {
        float* dst = cb + (size_t)slot * 32;
#pragma unroll
        for (int dh = 0; dh < 2; dh++)
#pragma unroll
            for (int c = 0; c < 4; c++) {
                const f32x4 v = {accO[dh][c * 4 + 0], accO[dh][c * 4 + 1],
                                 accO[dh][c * 4 + 2], accO[dh][c * 4 + 3]};
                *(f32x4*)(dst + (((dh * 4 + c) ^ s7) << 2)) = v;
            }
        if (lane < 32) lsh[qh][lane] = lsum2;
    }
    __syncthreads();
    if (wm == 0) {
        const float* src = cb + (size_t)slot * 32;
        const float lt = lsum2 + lsh[qh][l31];
#pragma unroll
        for (int dh = 0; dh < 2; dh++)
#pragma unroll
            for (int c = 0; c < 4; c++) {
                const f32x4 v = *(const f32x4*)(src + (((dh * 4 + c) ^ s7) << 2));
                accO[dh][c * 4 + 0] += v.x;
                accO[dh][c * 4 + 1] += v.y;
                accO[dh][c * 4 + 2] += v.z;
                accO[dh][c * 4 + 3] += v.w;
            }
        if (lane < 32) lsh2[qh][lane] = 1.0f / lt;
    }
    __syncthreads();
    if (wm == 0) {
#pragma unroll
        for (int r = 0; r < 16; r++) {
            const int ql = (r & 3) + 8 * (r >> 2) + 4 * hi;
            const float linv = lsh2[qh][ql];
            const int qg = q0 + qh * 32 + ql;
#pragma unroll
            for (int dh = 0; dh < 2; dh++) {
                float v = accO[dh][r] * linv;
                v = v >= 0.f ? v : 0.01f * v;
                attnL[((size_t)b * 2048 + qg) * 1024 + hh * 64 + dh * 32 + l31] = f2bf(v);
            }
        }
    }
}

// ---------------- launcher ----------------
extern "C" void kernel_launch(void* const* d_in, const int* in_sizes, int n_in,
                              void* d_out, int out_size, void* d_ws, size_t ws_size,
                              hipStream_t stream) {
    const float* Z     = (const float*)d_in[0];
    const float* nmask = (const float*)d_in[1];
    const float* pmask = (const float*)d_in[2];
    const float* ln1_g = (const float*)d_in[3];
    const float* ln1_b = (const float*)d_in[4];
    const float* qkv_w = (const float*)d_in[5];
    const float* qkv_b = (const float*)d_in[6];
    const float* o_w   = (const float*)d_in[7];
    const float* ln2_g = (const float*)d_in[8];
    const float* ln2_b = (const float*)d_in[9];
    const float* p1_w  = (const float*)d_in[10];
    const float* p1_b  = (const float*)d_in[11];
    const float* p2_w  = (const float*)d_in[12];
    const float* p2_b  = (const float*)d_in[13];
    float* out = (float*)d_out;

    char* w = (char*)d_ws;
    auto take = [&](size_t bytes) -> char* {
        char* p = w;
        w += (bytes + 255) & ~(size_t)255;
        return p;
    };
    u16* qkvW   = (u16*)take((size_t)3072 * 1024 * 2);
    u16* oW     = (u16*)take((size_t)1024 * 1024 * 2);
    u16* p1W    = (u16*)take((size_t)4096 * 1024 * 2);
    u16* p2W    = (u16*)take((size_t)1024 * 4096 * 2);
    u16* Zn     = (u16*)take((size_t)4096 * 1024 * 2);   // reused for Zn2
    u16* Qb     = (u16*)take((size_t)32 * 2048 * 64 * 2);
    u16* Kb     = (u16*)take((size_t)32 * 2048 * 64 * 2);
    u16* Vt     = (u16*)take((size_t)32 * 64 * 2048 * 2);
    u16* attnL  = (u16*)take((size_t)4096 * 1024 * 2);
    float* Z1   = (float*)take((size_t)4096 * 1024 * 4);
    u16* hbuf   = (u16*)take((size_t)4096 * 4096 * 2);   // 33.55 MB
    unsigned* Mp = (unsigned*)take((size_t)2 * 2048 * 2048 * 4);  // 33.55 MB
    float* pbias = (float*)take((size_t)3072 * 4);
    float* Vsc    = (float*)hbuf;          // alias: dead before hbuf written
    float* part01 = (float*)Mp;            // alias: Mp dead after attention
    float* part23 = (float*)hbuf;          // alias: hbuf dead during o-proj

    // merged prep (casts + bias permute + dense mask transpose-pack)
    prep_all<<<dim3(16385), 256, 0, stream>>>(qkv_w, o_w, p1_w, p2_w, qkv_b, nmask, pmask,
                                              qkvW, oW, p1W, p2W, pbias, Mp);
    // LN1
    ln_bf16<<<dim3(4096), 256, 0, stream>>>(Z, ln1_g, ln1_b, Zn);
    // QKV projection: V -> f32 scratch (dense), Q/K -> bf16 [BH][N][64]
    gemm_bt<0><<<dim3(24, 32), 256, 0, stream>>>(Zn, qkvW, pbias, Vsc, Qb, Kb, 4096, 3072, 1024, 1024);
    // V transpose -> Vt [BH][64][2048] (PV k-order columns, dense writes)
    vtrans<<<dim3(32, 32), 256, 0, stream>>>(Vsc, Vt);
    // attention (4 blocks/CU, mask-init in-register softmax)
    attn_fused9<<<dim3(1024), 256, 0, stream>>>(Qb, Kb, Vt, Mp, attnL);
    // o-projection, split-K=4 -> f32 partials (p0,p1 in Mp; p2,p3 in hbuf)
    gemm_bt<4><<<dim3(8, 32, 4), 256, 0, stream>>>(attnL, oW, nullptr, part01, part23, nullptr,
                                                   4096, 1024, 256, 1024);
    // 4-way combine + residual + LN2 (writes Z1 and Zn)
    ln2_comb4<<<dim3(4096), 256, 0, stream>>>(part01, part01 + (size_t)4096 * 1024,
                                              part23, part23 + (size_t)4096 * 1024,
                                              Z, ln2_g, ln2_b, Z1, Zn);
    // MLP up + relu -> hbuf (bf16)
    gemm_bt<2><<<dim3(32, 32), 256, 0, stream>>>(Zn, p1W, p1_b, hbuf, nullptr, nullptr,
                                                 4096, 4096, 1024, 1024);
    // MLP down, split-K=2 -> f32 partials in Mp
    gemm_bt<4><<<dim3(8, 32, 2), 256, 0, stream>>>(hbuf, p2W, nullptr, part01, nullptr, nullptr,
                                                   4096, 1024, 2048, 4096);
    // final combine -> out
    out_comb<<<dim3(4096), 256, 0, stream>>>(part01, part01 + (size_t)4096 * 1024, p2_b, Z1, out);
}

// Round 7
// 408.808 us; speedup vs baseline: 1.0999x; 1.0999x over previous
//
#include <hip/hip_runtime.h>

typedef unsigned short u16;
typedef __attribute__((ext_vector_type(8))) short bf16x8;
typedef __attribute__((ext_vector_type(2))) float f32x2;
typedef __attribute__((ext_vector_type(4))) float f32x4;
typedef __attribute__((ext_vector_type(16))) float f32x16;
typedef __attribute__((ext_vector_type(4))) unsigned u32x4;

#define DEV static __device__ __forceinline__

DEV u16 f2bf(float f) {
    unsigned u = __float_as_uint(f);
    u += 0x7FFFu + ((u >> 16) & 1u);
    return (u16)(u >> 16);
}

DEV float uaf(unsigned u) { return __uint_as_float(u); }

typedef const __attribute__((address_space(1))) void* gas1_t;
typedef __attribute__((address_space(3))) void* gas3_t;

DEV void gl_lds16(const u16* g, u16* l) {
    __builtin_amdgcn_global_load_lds((gas1_t)g, (gas3_t)l, 16, 0, 0);
}

DEV unsigned cvtpk_bf16(float a, float b) {
    unsigned r;
    asm("v_cvt_pk_bf16_f32 %0, %1, %2" : "=v"(r) : "v"(a), "v"(b));
    return r;
}

// swizzled LDS offset (u16 units) for 128B rows of 64 u16, 16B chunks
DEV int sw8(int row, int chunk) { return row * 64 + ((chunk ^ (row & 7)) << 3); }

// ---------------- merged prep: weight casts + bias permute + mask pack + LN1 ----------------
// block ranges: [0,3072) qkvW | [3072,4096) oW | [4096,8192) p1W | [8192,12288) p2W
//               | [12288,16384) mask transpose-pack | [16384,20480) LN1 | 20480 pbias
__global__ __launch_bounds__(256) void prep_all(const float* __restrict__ qkv_w,
                                                const float* __restrict__ o_w,
                                                const float* __restrict__ p1_w,
                                                const float* __restrict__ p2_w,
                                                const float* __restrict__ qkv_b,
                                                const float* __restrict__ nm,
                                                const float* __restrict__ pm,
                                                const float* __restrict__ Z,
                                                const float* __restrict__ ln1_g,
                                                const float* __restrict__ ln1_b,
                                                u16* __restrict__ qkvW,
                                                u16* __restrict__ oW,
                                                u16* __restrict__ p1W,
                                                u16* __restrict__ p2W,
                                                float* __restrict__ pbias,
                                                unsigned* __restrict__ Mp,
                                                u16* __restrict__ Zn) {
    __shared__ uint4 Ls[512];   // 8KB, used only by the mask branch
    __shared__ float rs[4], rss[4];
    const int bid = blockIdx.x, t = threadIdx.x;
    if (bid < 3072) {            // qkv cast + row permute: rows = [V|Q|K], each h*64+t
        int i = bid * 256 + t;
        int orow = i >> 8, cc = i & 255;
        int region = orow >> 10, rem = orow & 1023, h = rem >> 6, tt = rem & 63;
        int srow = h * 192 + region * 64 + tt;
        float4 v = ((const float4*)qkv_w)[srow * 256 + cc];
        ushort4 o;
        o.x = f2bf(v.x); o.y = f2bf(v.y); o.z = f2bf(v.z); o.w = f2bf(v.w);
        ((ushort4*)qkvW)[i] = o;
    } else if (bid < 4096) {     // o_w cast
        int i = (bid - 3072) * 256 + t;
        float4 v = ((const float4*)o_w)[i];
        ushort4 o;
        o.x = f2bf(v.x); o.y = f2bf(v.y); o.z = f2bf(v.z); o.w = f2bf(v.w);
        ((ushort4*)oW)[i] = o;
    } else if (bid < 8192) {     // p1_w cast
        int i = (bid - 4096) * 256 + t;
        float4 v = ((const float4*)p1_w)[i];
        ushort4 o;
        o.x = f2bf(v.x); o.y = f2bf(v.y); o.z = f2bf(v.z); o.w = f2bf(v.w);
        ((ushort4*)p1W)[i] = o;
    } else if (bid < 12288) {    // p2_w cast
        int i = (bid - 8192) * 256 + t;
        float4 v = ((const float4*)p2_w)[i];
        ushort4 o;
        o.x = f2bf(v.x); o.y = f2bf(v.y); o.z = f2bf(v.z); o.w = f2bf(v.w);
        ((ushort4*)p2W)[i] = o;
    } else if (bid < 16384) {    // mask pack: LDS-transposed, dense in and out
        // tile = one b, one mt (32 m), 64 n. layout out: [b][mt][c][n][hi] uint4
        const int idx = bid - 12288;
        const int bb = idx >> 11, r2 = idx & 2047;
        const int mt = r2 >> 5, nt = r2 & 31;
        const int n0 = nt * 64;
        // read: 2 consecutive float4 (8 m) per array per thread, coalesced
        const int n = t >> 2;
        const int mq0 = (t & 3) * 2;
        const size_t fbase = (size_t)bb * 1048576 + (size_t)(n0 + n) * 512 + mt * 8 + mq0;
        const float4 a0 = ((const float4*)nm)[fbase];
        const float4 a1 = ((const float4*)nm)[fbase + 1];
        const float4 b0 = ((const float4*)pm)[fbase];
        const float4 b1 = ((const float4*)pm)[fbase + 1];
        uint4 o0, o1;
        o0.x = ((unsigned)f2bf(b0.x) << 16) | f2bf(a0.x * 1.4426950f);
        o0.y = ((unsigned)f2bf(b0.y) << 16) | f2bf(a0.y * 1.4426950f);
        o0.z = ((unsigned)f2bf(b0.z) << 16) | f2bf(a0.z * 1.4426950f);
        o0.w = ((unsigned)f2bf(b0.w) << 16) | f2bf(a0.w * 1.4426950f);
        o1.x = ((unsigned)f2bf(b1.x) << 16) | f2bf(a1.x * 1.4426950f);
        o1.y = ((unsigned)f2bf(b1.y) << 16) | f2bf(a1.y * 1.4426950f);
        o1.z = ((unsigned)f2bf(b1.z) << 16) | f2bf(a1.z * 1.4426950f);
        o1.w = ((unsigned)f2bf(b1.w) << 16) | f2bf(a1.w * 1.4426950f);
        // slot: m5 = 8c + 4hi + {0..3};  mq0 even -> (c=mq0>>1, hi=0), mq0+1 -> hi=1
        const int c = mq0 >> 1;
        Ls[c * 128 + n * 2 + 0] = o0;
        Ls[c * 128 + n * 2 + 1] = o1;
        __syncthreads();
        // write: per c, 128 consecutive uint4 (2KB) fully coalesced
        const int wc = t >> 6, j = t & 63;
        const size_t obase = (((size_t)(bb * 64 + mt) * 4) + wc) * 4096 + (size_t)n0 * 2;
        ((uint4*)Mp)[obase + j] = Ls[wc * 128 + j];
        ((uint4*)Mp)[obase + 64 + j] = Ls[wc * 128 + 64 + j];
    } else if (bid < 20480) {    // LN1: one row per block
        const int row = bid - 16384;
        const float4 v = ((const float4*)(Z + (size_t)row * 1024))[t];
        float s = v.x + v.y + v.z + v.w;
        float ss = v.x * v.x + v.y * v.y + v.z * v.z + v.w * v.w;
#pragma unroll
        for (int o = 1; o < 64; o <<= 1) {
            s += __shfl_xor(s, o);
            ss += __shfl_xor(ss, o);
        }
        const int wave = t >> 6, lane = t & 63;
        if (lane == 0) { rs[wave] = s; rss[wave] = ss; }
        __syncthreads();
        const float tot = rs[0] + rs[1] + rs[2] + rs[3];
        const float totss = rss[0] + rss[1] + rss[2] + rss[3];
        const float mu = tot * (1.0f / 1024.0f);
        const float var = totss * (1.0f / 1024.0f) - mu * mu;
        const float rstd = rsqrtf(var + 1e-5f);
        const float4 g4 = ((const float4*)ln1_g)[t];
        const float4 b4 = ((const float4*)ln1_b)[t];
        ushort4 o;
        o.x = f2bf((v.x - mu) * rstd * g4.x + b4.x);
        o.y = f2bf((v.y - mu) * rstd * g4.y + b4.y);
        o.z = f2bf((v.z - mu) * rstd * g4.z + b4.z);
        o.w = f2bf((v.w - mu) * rstd * g4.w + b4.w);
        ((ushort4*)(Zn + (size_t)row * 1024))[t] = o;
    } else {                     // qkv bias permute (3072 elements)
#pragma unroll
        for (int k = 0; k < 12; k++) {
            int i = k * 256 + t;
            int region = i >> 10, rem = i & 1023, h = rem >> 6, tt = rem & 63;
            pbias[i] = qkv_b[h * 192 + region * 64 + tt];
        }
    }
}

// ---- fused 2-way combine + residual + LayerNorm ----
__global__ __launch_bounds__(256) void ln2_comb2(const float* __restrict__ p0,
                                                 const float* __restrict__ p1,
                                                 const float* __restrict__ Z,
                                                 const float* __restrict__ gam,
                                                 const float* __restrict__ bet,
                                                 float* __restrict__ Z1,
                                                 u16* __restrict__ y) {
    const int row = blockIdx.x;
    const int t = threadIdx.x;
    const size_t off = (size_t)row * 256 + t;
    const float4 a = ((const float4*)p0)[off];
    const float4 c = ((const float4*)p1)[off];
    const float4 z = ((const float4*)Z)[off];
    float4 v;
    v.x = a.x + c.x + z.x;
    v.y = a.y + c.y + z.y;
    v.z = a.z + c.z + z.z;
    v.w = a.w + c.w + z.w;
    ((float4*)Z1)[off] = v;
    float s = v.x + v.y + v.z + v.w;
    float ss = v.x * v.x + v.y * v.y + v.z * v.z + v.w * v.w;
#pragma unroll
    for (int o = 1; o < 64; o <<= 1) {
        s += __shfl_xor(s, o);
        ss += __shfl_xor(ss, o);
    }
    __shared__ float rs[4], rss[4];
    const int wave = t >> 6, lane = t & 63;
    if (lane == 0) { rs[wave] = s; rss[wave] = ss; }
    __syncthreads();
    const float tot = rs[0] + rs[1] + rs[2] + rs[3];
    const float totss = rss[0] + rss[1] + rss[2] + rss[3];
    const float mu = tot * (1.0f / 1024.0f);
    const float var = totss * (1.0f / 1024.0f) - mu * mu;
    const float rstd = rsqrtf(var + 1e-5f);
    const float4 g4 = ((const float4*)gam)[t];
    const float4 b4 = ((const float4*)bet)[t];
    ushort4 o;
    o.x = f2bf((v.x - mu) * rstd * g4.x + b4.x);
    o.y = f2bf((v.y - mu) * rstd * g4.y + b4.y);
    o.z = f2bf((v.z - mu) * rstd * g4.z + b4.z);
    o.w = f2bf((v.w - mu) * rstd * g4.w + b4.w);
    ((ushort4*)(y + (size_t)row * 1024))[t] = o;
}

// ---- final combine: out = p0 + p1 + bias + Z1 ----
__global__ __launch_bounds__(256) void out_comb(const float* __restrict__ p0,
                                                const float* __restrict__ p1,
                                                const float* __restrict__ bias,
                                                const float* __restrict__ Z1,
                                                float* __restrict__ out) {
    int i = blockIdx.x * 256 + threadIdx.x;   // 1048576 float4s
    float4 a = ((const float4*)p0)[i];
    float4 c = ((const float4*)p1)[i];
    float4 z = ((const float4*)Z1)[i];
    float4 b = ((const float4*)bias)[i & 255];
    float4 o;
    o.x = a.x + c.x + z.x + b.x; o.y = a.y + c.y + z.y + b.y;
    o.z = a.z + c.z + z.z + b.z; o.w = a.w + c.w + z.w + b.w;
    ((float4*)out)[i] = o;
}

// ---------------- GEMM v9: double-buffered, sw4-swizzled, XCD-chunked ----------------
// C[M,N] = A[M,K-slice] @ Bt[N,K-slice]^T. 128x128 tile, BK=32, 2 k-steps/iter.
// EPI 0: +pbias; region: 0 -> f32 Vsc(out0), 1 -> Q bf16(out1), 2 -> K bf16(out2)
// EPI 2: +bias, relu, write bf16 out0
// EPI 4: raw f32 partial -> out0 + z*M*N
template <int EPI>
__global__ __launch_bounds__(256, 3) void gemm_bt(const u16* __restrict__ A,
                                                  const u16* __restrict__ Bt,
                                                  const float* __restrict__ bias,
                                                  void* __restrict__ out0,
                                                  void* __restrict__ out1,
                                                  void* __restrict__ out2,
                                                  int M, int N, int K, int ldk) {
    __shared__ __align__(16) u16 As[2][128 * 32];
    __shared__ __align__(16) u16 Bs[2][128 * 32];
    const int tid = threadIdx.x;
    const int wave = tid >> 6, lane = tid & 63;
    const int lhi = lane >> 4, llo = lane & 15;
    // XCD-chunked block swizzle (nwg_xy is a multiple of 8 for all call sites)
    const int gx = gridDim.x;
    const int bid = blockIdx.y * gx + blockIdx.x;
    const int swz = (bid & 7) * ((gx * gridDim.y) >> 3) + (bid >> 3);
    const int bx = swz % gx, by = swz / gx;
    const int kz = blockIdx.z * K;

    const int arow = wave * 32 + (lane >> 2);
    const int asw = ((lane & 3) ^ ((lane >> 2) & 3)) << 3;  // pre-swizzled source col
    const u16* gA = A + (size_t)(by * 128 + arow) * ldk + kz + asw;
    const u16* gB = Bt + (size_t)(bx * 128 + arow) * ldk + kz + asw;
    u16* lA0 = As[0] + wave * 1024 + lane * 8;
    u16* lA1 = As[1] + wave * 1024 + lane * 8;
    u16* lB0 = Bs[0] + wave * 1024 + lane * 8;
    u16* lB1 = Bs[1] + wave * 1024 + lane * 8;

#define GSTAGE(LA, LB) do { \
        gl_lds16(gA, LA); gl_lds16(gA + 16 * (size_t)ldk, (LA) + 512); \
        gl_lds16(gB, LB); gl_lds16(gB + 16 * (size_t)ldk, (LB) + 512); \
        gA += 32; gB += 32; } while (0)

    const int wr = wave >> 1, wc = wave & 1;
    const f32x4 zero = {0.f, 0.f, 0.f, 0.f};
    f32x4 acc[4][4];
#pragma unroll
    for (int i = 0; i < 4; i++)
#pragma unroll
        for (int j = 0; j < 4; j++) acc[i][j] = zero;

    // sw4 read offsets: row r, global chunk lhi lives at LDS chunk (lhi ^ (r&3))
#define GCOMP(AB, BB) do { \
        bf16x8 af[4], bfr[4]; \
        _Pragma("unroll") \
        for (int i = 0; i < 4; i++) { \
            const int r = wr * 64 + i * 16 + llo; \
            af[i] = *(const bf16x8*)((AB) + r * 32 + (((lhi ^ r) & 3) << 3)); \
        } \
        _Pragma("unroll") \
        for (int j = 0; j < 4; j++) { \
            const int r = wc * 64 + j * 16 + llo; \
            bfr[j] = *(const bf16x8*)((BB) + r * 32 + (((lhi ^ r) & 3) << 3)); \
        } \
        __builtin_amdgcn_s_setprio(1); \
        _Pragma("unroll") \
        for (int i = 0; i < 4; i++) \
            _Pragma("unroll") \
            for (int j = 0; j < 4; j++) \
                acc[i][j] = __builtin_amdgcn_mfma_f32_16x16x32_bf16(af[i], bfr[j], acc[i][j], 0, 0, 0); \
        __builtin_amdgcn_s_setprio(0); \
        __syncthreads(); } while (0)

    // 2-phase pipeline: stage(next) issued before compute(cur); 1 barrier/step
    GSTAGE(lA0, lB0);
    __syncthreads();
    for (int k0 = 0; k0 < K; k0 += 64) {
        if (k0 + 32 < K) GSTAGE(lA1, lB1);
        GCOMP(As[0], Bs[0]);
        if (k0 + 64 < K) GSTAGE(lA0, lB0);
        GCOMP(As[1], Bs[1]);
    }
#undef GCOMP
#undef GSTAGE

    const int rbase = by * 128 + wr * 64 + lhi * 4;
    const int cbase = bx * 128 + wc * 64 + llo;
    float* pout = nullptr;
    if constexpr (EPI == 4) {
        pout = (float*)out0 + (size_t)blockIdx.z * M * N;
    }
#pragma unroll
    for (int i = 0; i < 4; i++) {
#pragma unroll
        for (int j = 0; j < 4; j++) {
#pragma unroll
            for (int r = 0; r < 4; r++) {
                const int row = rbase + i * 16 + r;
                const int col = cbase + j * 16;
                float v = acc[i][j][r];
                if constexpr (EPI == 0) {
                    v += bias[col];
                    const int region = col >> 10;   // uniform per block
                    const int c = col & 1023;       // h*64 + t
                    const int b = row >> 11, n = row & 2047;
                    if (region == 0) {
                        ((float*)out0)[(size_t)row * 1024 + c] = v;  // Vsc f32
                    } else {
                        const int h = c >> 6, t = c & 63;
                        u16* dst = (region == 1) ? (u16*)out1 : (u16*)out2;
                        dst[(((size_t)(b * 16 + h)) * 2048 + n) * 64 + t] = f2bf(v);
                    }
                } else if constexpr (EPI == 2) {
                    v += bias[col];
                    v = v > 0.f ? v : 0.f;
                    ((u16*)out0)[(size_t)row * N + col] = f2bf(v);
                } else {
                    pout[(size_t)row * N + col] = v;
                }
            }
        }
    }
}

// ---------------- V transpose: Vsc f32 [B*N][1024] -> Vt bf16 [BH][64][2048] --
// m-columns written in PV k-order (pg permutation within each 32-m block).
__global__ __launch_bounds__(256) void vtrans(const float* __restrict__ Vsc,
                                              u16* __restrict__ Vt) {
    __shared__ u16 Ts[64 * 72];
    const int nt = blockIdx.x;  // n-tile (0..31)
    const int bh = blockIdx.y;  // 0..31
    const int b = bh >> 4, h = bh & 15;
    const int t = threadIdx.x;
    const int n0 = nt * 64;
    const int nr = t >> 2;
    const int dq = (t & 3) * 16;
    const float* src = Vsc + ((size_t)(b * 2048 + n0 + nr)) * 1024 + h * 64 + dq;
    float4 v0 = ((const float4*)src)[0];
    float4 v1 = ((const float4*)src)[1];
    float4 v2 = ((const float4*)src)[2];
    float4 v3 = ((const float4*)src)[3];
    u16* c0 = Ts + nr;
    c0[(dq + 0) * 72]  = f2bf(v0.x); c0[(dq + 1) * 72]  = f2bf(v0.y);
    c0[(dq + 2) * 72]  = f2bf(v0.z); c0[(dq + 3) * 72]  = f2bf(v0.w);
    c0[(dq + 4) * 72]  = f2bf(v1.x); c0[(dq + 5) * 72]  = f2bf(v1.y);
    c0[(dq + 6) * 72]  = f2bf(v1.z); c0[(dq + 7) * 72]  = f2bf(v1.w);
    c0[(dq + 8) * 72]  = f2bf(v2.x); c0[(dq + 9) * 72]  = f2bf(v2.y);
    c0[(dq + 10) * 72] = f2bf(v2.z); c0[(dq + 11) * 72] = f2bf(v2.w);
    c0[(dq + 12) * 72] = f2bf(v3.x); c0[(dq + 13) * 72] = f2bf(v3.y);
    c0[(dq + 14) * 72] = f2bf(v3.z); c0[(dq + 15) * 72] = f2bf(v3.w);
    __syncthreads();
    const int d = t >> 2, n8 = (t & 3) * 16;
    u16* dstrow = Vt + ((size_t)bh * 64 + d) * 2048 + n0;
#pragma unroll
    for (int w = 0; w < 4; w++) {
        const int gi = (n8 >> 2) + w;          // m-group id within 64-tile
        const int g5 = gi & 7, blk = gi >> 3;
        const int pg = (g5 & 4) | ((g5 & 1) << 1) | ((g5 >> 1) & 1);
        *(uint2*)(dstrow + blk * 32 + pg * 4) = *(const uint2*)(Ts + d * 72 + n8 + w * 4);
    }
}

// ---------------- fused flash-style attention v8 (proven 70us config) ----------------
__global__ __launch_bounds__(256, 4) void attn_fused8(const u16* __restrict__ Qg,
                                                      const u16* __restrict__ Kg,
                                                      const u16* __restrict__ Vtg,
                                                      const unsigned* __restrict__ Mp,
                                                      u16* __restrict__ attnL) {
    __shared__ __align__(16) u16 Ks[2][64 * 64];
    __shared__ __align__(16) u16 Vs[2][64 * 64];
    __shared__ float lsh[2][32], lsh2[2][32];
    const int tid = threadIdx.x, wave = tid >> 6, lane = tid & 63;
    const int qh = wave & 1, wm = wave >> 1;       // q-half, m-split
    const int hi = lane >> 5, l31 = lane & 31;
    // XCD-grouped block decode: 16 heads of a (b,qt) group on one XCD
    const int pid = blockIdx.x;
    const int seq = pid >> 3;
    const int hh = seq & 15;
    const int g = (pid & 7) + (seq >> 4) * 8;
    const int b = g >> 5, qt = g & 31;
    const int bh = b * 16 + hh;
    const int q0 = qt * 64;

    // loop-carried staging pointers
    const int l3 = lane >> 3, l7 = lane & 7;
    const int swcol = (l7 ^ l3) << 3;
    const int srow = wave * 16 + l3;
    const u16* kp = Kg + ((size_t)bh * 2048 + srow) * 64 + swcol;
    const u16* vp = Vtg + ((size_t)bh * 64 + srow) * 2048 + swcol;
    u16* lKa = Ks[0] + wave * 1024 + lane * 8;
    u16* lKb = Ks[1] + wave * 1024 + lane * 8;
    u16* lVa = Vs[0] + wave * 1024 + lane * 8;
    u16* lVb = Vs[1] + wave * 1024 + lane * 8;

#define STAGE(LK, LV) do { \
        gl_lds16(kp, LK); gl_lds16(kp + 512, (LK) + 512); \
        gl_lds16(vp, LV); gl_lds16(vp + 16384, (LV) + 512); \
        kp += 4096; vp += 64; } while (0)

    // prologue: stage tile 0, Q fragments to registers
    STAGE(lKa, lVa);
    const int qrow = q0 + qh * 32 + l31;
    const u16* qptr = Qg + ((size_t)bh * 2048 + qrow) * 64 + hi * 8;
    bf16x8 qf[4];
#pragma unroll
    for (int ks = 0; ks < 4; ks++) qf[ks] = *(const bf16x8*)(qptr + ks * 16);

    // coalesced mask base: [b][mt][c][n][hi] (uint4 units), mt = 2t + wm
    const uint4* mp = (const uint4*)Mp + (size_t)(b * 64 + wm) * 16384
                                       + (size_t)qrow * 2 + hi;

    const f32x16 z16 = {0.f,0.f,0.f,0.f,0.f,0.f,0.f,0.f,0.f,0.f,0.f,0.f,0.f,0.f,0.f,0.f};
    f32x16 accO[2];
    accO[0] = z16; accO[1] = z16;
    f32x2 lsv = {0.f, 0.f};
    const float CS = 0.125f * 1.4426950f;
    const f32x2 csv = {CS, CS};
    __syncthreads();

#define QUAD(M, q) { \
        f32x2 nm0 = {uaf(M.x << 16), uaf(M.y << 16)}; \
        f32x2 nm1 = {uaf(M.z << 16), uaf(M.w << 16)}; \
        const f32x2 sa = {sacc[q], sacc[q + 1]}; \
        const f32x2 sb = {sacc[q + 2], sacc[q + 3]}; \
        nm0 += sa * csv; nm1 += sb * csv; \
        f32x2 e0 = {__builtin_amdgcn_exp2f(nm0.x), __builtin_amdgcn_exp2f(nm0.y)}; \
        f32x2 e1 = {__builtin_amdgcn_exp2f(nm1.x), __builtin_amdgcn_exp2f(nm1.y)}; \
        lsv += e0; lsv += e1; \
        const f32x2 pm0 = {uaf(M.x & 0xFFFF0000u), uaf(M.y & 0xFFFF0000u)}; \
        const f32x2 pm1 = {uaf(M.z & 0xFFFF0000u), uaf(M.w & 0xFFFF0000u)}; \
        e0 *= pm0; e1 *= pm1; \
        wpk[(q) / 2] = cvtpk_bf16(e0.x, e0.y); \
        wpk[(q) / 2 + 1] = cvtpk_bf16(e1.x, e1.y); }

    // masks for CURRENT tile load first (4 VMEM), then next-tile STAGE (8 VMEM):
    // the softmax's wait on masks leaves the stage loads in flight; the barrier
    // at iter end drains the stage.
#define ITER(KSB, VSB, LK, LV, DO_STAGE) do { \
        const uint4 M0 = mp[0], M1 = mp[4096], M2 = mp[8192], M3 = mp[12288]; \
        mp += 32768; \
        if (DO_STAGE) STAGE(LK, LV); \
        f32x16 sacc = z16; \
        __builtin_amdgcn_s_setprio(1); \
        _Pragma("unroll") \
        for (int ks = 0; ks < 4; ks++) { \
            const bf16x8 kf = *(const bf16x8*)((KSB) + sw8(wm * 32 + l31, ks * 2 + hi)); \
            sacc = __builtin_amdgcn_mfma_f32_32x32x16_bf16(kf, qf[ks], sacc, 0, 0, 0); \
        } \
        __builtin_amdgcn_s_setprio(0); \
        unsigned wpk[8]; \
        QUAD(M0, 0) QUAD(M1, 4) QUAD(M2, 8) QUAD(M3, 12) \
        const u32x4 fa0v = {wpk[0], wpk[1], wpk[2], wpk[3]}; \
        const u32x4 fa1v = {wpk[4], wpk[5], wpk[6], wpk[7]}; \
        const bf16x8 pa0 = __builtin_bit_cast(bf16x8, fa0v); \
        const bf16x8 pa1 = __builtin_bit_cast(bf16x8, fa1v); \
        __builtin_amdgcn_s_setprio(1); \
        _Pragma("unroll") \
        for (int dh = 0; dh < 2; dh++) { \
            const bf16x8 vf0 = *(const bf16x8*)((VSB) + sw8(dh * 32 + l31, wm * 4 + hi)); \
            accO[dh] = __builtin_amdgcn_mfma_f32_32x32x16_bf16(pa0, vf0, accO[dh], 0, 0, 0); \
            const bf16x8 vf1 = *(const bf16x8*)((VSB) + sw8(dh * 32 + l31, wm * 4 + 2 + hi)); \
            accO[dh] = __builtin_amdgcn_mfma_f32_32x32x16_bf16(pa1, vf1, accO[dh], 0, 0, 0); \
        } \
        __builtin_amdgcn_s_setprio(0); \
        __syncthreads(); } while (0)

    for (int tt = 0; tt < 16; tt++) {
        ITER(Ks[0], Vs[0], lKb, lVb, true);          // even tile 2tt; stage 2tt+1
        ITER(Ks[1], Vs[1], lKa, lVa, (tt < 15));     // odd tile 2tt+1; stage 2tt+2
    }
#undef ITER
#undef QUAD
#undef STAGE

    // combine the wm pair (same qh): conflict-free XOR-swizzled LDS buffer
    const float lsum = lsv.x + lsv.y;
    const float lsum2 = lsum + __shfl_xor(lsum, 32);
    float* cb = (float*)&Ks[0][0];   // 16 KB: 128 slots x 32 floats, swizzled
    const int slot = qh * 64 + lane;
    const int s7 = slot & 7;
    if (wm == 1) {
        float* dst = cb + (size_t)slot * 32;
#pragma unroll
        for (int dh = 0; dh < 2; dh++)
#pragma unroll
            for (int c = 0; c < 4; c++) {
                const f32x4 v = {accO[dh][c * 4 + 0], accO[dh][c * 4 + 1],
                                 accO[dh][c * 4 + 2], accO[dh][c * 4 + 3]};
                *(f32x4*)(dst + (((dh * 4 + c) ^ s7) << 2)) = v;
            }
        if (lane < 32) lsh[qh][lane] = lsum2;
    }
    __syncthreads();
    if (wm == 0) {
        const float* src = cb + (size_t)slot * 32;
        const float lt = lsum2 + lsh[qh][l31];
#pragma unroll
        for (int dh = 0; dh < 2; dh++)
#pragma unroll
            for (int c = 0; c < 4; c++) {
                const f32x4 v = *(const f32x4*)(src + (((dh * 4 + c) ^ s7) << 2));
                accO[dh][c * 4 + 0] += v.x;
                accO[dh][c * 4 + 1] += v.y;
                accO[dh][c * 4 + 2] += v.z;
                accO[dh][c * 4 + 3] += v.w;
            }
        if (lane < 32) lsh2[qh][lane] = 1.0f / lt;
    }
    __syncthreads();
    if (wm == 0) {
#pragma unroll
        for (int r = 0; r < 16; r++) {
            const int ql = (r & 3) + 8 * (r >> 2) + 4 * hi;
            const float linv = lsh2[qh][ql];
            const int qg = q0 + qh * 32 + ql;
#pragma unroll
            for (int dh = 0; dh < 2; dh++) {
                float v = accO[dh][r] * linv;
                v = v >= 0.f ? v : 0.01f * v;
                attnL[((size_t)b * 2048 + qg) * 1024 + hh * 64 + dh * 32 + l31] = f2bf(v);
            }
        }
    }
}

// ---------------- launcher ----------------
extern "C" void kernel_launch(void* const* d_in, const int* in_sizes, int n_in,
                              void* d_out, int out_size, void* d_ws, size_t ws_size,
                              hipStream_t stream) {
    const float* Z     = (const float*)d_in[0];
    const float* nmask = (const float*)d_in[1];
    const float* pmask = (const float*)d_in[2];
    const float* ln1_g = (const float*)d_in[3];
    const float* ln1_b = (const float*)d_in[4];
    const float* qkv_w = (const float*)d_in[5];
    const float* qkv_b = (const float*)d_in[6];
    const float* o_w   = (const float*)d_in[7];
    const float* ln2_g = (const float*)d_in[8];
    const float* ln2_b = (const float*)d_in[9];
    const float* p1_w  = (const float*)d_in[10];
    const float* p1_b  = (const float*)d_in[11];
    const float* p2_w  = (const float*)d_in[12];
    const float* p2_b  = (const float*)d_in[13];
    float* out = (float*)d_out;

    char* w = (char*)d_ws;
    auto take = [&](size_t bytes) -> char* {
        char* p = w;
        w += (bytes + 255) & ~(size_t)255;
        return p;
    };
    u16* qkvW   = (u16*)take((size_t)3072 * 1024 * 2);
    u16* oW     = (u16*)take((size_t)1024 * 1024 * 2);
    u16* p1W    = (u16*)take((size_t)4096 * 1024 * 2);
    u16* p2W    = (u16*)take((size_t)1024 * 4096 * 2);
    u16* Zn     = (u16*)take((size_t)4096 * 1024 * 2);   // reused for Zn2
    u16* Qb     = (u16*)take((size_t)32 * 2048 * 64 * 2);
    u16* Kb     = (u16*)take((size_t)32 * 2048 * 64 * 2);
    u16* Vt     = (u16*)take((size_t)32 * 64 * 2048 * 2);
    u16* attnL  = (u16*)take((size_t)4096 * 1024 * 2);
    float* Z1   = (float*)take((size_t)4096 * 1024 * 4);
    u16* hbuf   = (u16*)take((size_t)4096 * 4096 * 2);   // 33.55 MB
    unsigned* Mp = (unsigned*)take((size_t)2 * 2048 * 2048 * 4);  // 33.55 MB
    float* pbias = (float*)take((size_t)3072 * 4);
    float* Vsc    = (float*)hbuf;          // alias: dead before hbuf written
    float* part01 = (float*)Mp;            // alias: Mp dead after attention
    float* part23 = (float*)hbuf;          // alias: hbuf dead during o-proj

    // merged prep (casts + bias permute + dense mask transpose-pack + LN1)
    prep_all<<<dim3(20481), 256, 0, stream>>>(qkv_w, o_w, p1_w, p2_w, qkv_b, nmask, pmask,
                                              Z, ln1_g, ln1_b,
                                              qkvW, oW, p1W, p2W, pbias, Mp, Zn);
    // QKV projection: V -> f32 scratch (dense), Q/K -> bf16 [BH][N][64]
    gemm_bt<0><<<dim3(24, 32), 256, 0, stream>>>(Zn, qkvW, pbias, Vsc, Qb, Kb, 4096, 3072, 1024, 1024);
    // V transpose -> Vt [BH][64][2048] (PV k-order columns, dense writes)
    vtrans<<<dim3(32, 32), 256, 0, stream>>>(Vsc, Vt);
    // attention (4 blocks/CU, in-register softmax)
    attn_fused8<<<dim3(1024), 256, 0, stream>>>(Qb, Kb, Vt, Mp, attnL);
    // o-projection, split-K=2 -> f32 partials in Mp (2 x 16.8 MB)
    gemm_bt<4><<<dim3(8, 32, 2), 256, 0, stream>>>(attnL, oW, nullptr, part01, nullptr, nullptr,
                                                   4096, 1024, 512, 1024);
    // 2-way combine + residual + LN2 (writes Z1 and Zn)
    ln2_comb2<<<dim3(4096), 256, 0, stream>>>(part01, part01 + (size_t)4096 * 1024,
                                              Z, ln2_g, ln2_b, Z1, Zn);
    // MLP up + relu -> hbuf (bf16)
    gemm_bt<2><<<dim3(32, 32), 256, 0, stream>>>(Zn, p1W, p1_b, hbuf, nullptr, nullptr,
                                                 4096, 4096, 1024, 1024);
    // MLP down, split-K=2 -> f32 partials in Mp
    gemm_bt<4><<<dim3(8, 32, 2), 256, 0, stream>>>(hbuf, p2W, nullptr, part01, nullptr, nullptr,
                                                   4096, 1024, 2048, 4096);
    // final combine -> out
    out_comb<<<dim3(4096), 256, 0, stream>>>(part01, part01 + (size_t)4096 * 1024, p2_b, Z1, out);
}

// Round 8
// 407.565 us; speedup vs baseline: 1.1032x; 1.0031x over previous
//
#include <hip/hip_runtime.h>

typedef unsigned short u16;
typedef __attribute__((ext_vector_type(8))) short bf16x8;
typedef __attribute__((ext_vector_type(2))) float f32x2;
typedef __attribute__((ext_vector_type(4))) float f32x4;
typedef __attribute__((ext_vector_type(16))) float f32x16;
typedef __attribute__((ext_vector_type(4))) unsigned u32x4;

#define DEV static __device__ __forceinline__

DEV u16 f2bf(float f) {
    unsigned u = __float_as_uint(f);
    u += 0x7FFFu + ((u >> 16) & 1u);
    return (u16)(u >> 16);
}

DEV float uaf(unsigned u) { return __uint_as_float(u); }

typedef const __attribute__((address_space(1))) void* gas1_t;
typedef __attribute__((address_space(3))) void* gas3_t;

DEV void gl_lds16(const u16* g, u16* l) {
    __builtin_amdgcn_global_load_lds((gas1_t)g, (gas3_t)l, 16, 0, 0);
}

DEV unsigned cvtpk_bf16(float a, float b) {
    unsigned r;
    asm("v_cvt_pk_bf16_f32 %0, %1, %2" : "=v"(r) : "v"(a), "v"(b));
    return r;
}

// swizzled LDS offset (u16 units) for 128B rows of 64 u16, 16B chunks
DEV int sw8(int row, int chunk) { return row * 64 + ((chunk ^ (row & 7)) << 3); }

// ---------------- merged prep: weight casts + bias permute + mask pack + LN1 ----------------
// block ranges: [0,3072) qkvW | [3072,4096) oW | [4096,8192) p1W | [8192,12288) p2W
//               | [12288,16384) mask transpose-pack | [16384,20480) LN1 | 20480 pbias
__global__ __launch_bounds__(256) void prep_all(const float* __restrict__ qkv_w,
                                                const float* __restrict__ o_w,
                                                const float* __restrict__ p1_w,
                                                const float* __restrict__ p2_w,
                                                const float* __restrict__ qkv_b,
                                                const float* __restrict__ nm,
                                                const float* __restrict__ pm,
                                                const float* __restrict__ Z,
                                                const float* __restrict__ ln1_g,
                                                const float* __restrict__ ln1_b,
                                                u16* __restrict__ qkvW,
                                                u16* __restrict__ oW,
                                                u16* __restrict__ p1W,
                                                u16* __restrict__ p2W,
                                                float* __restrict__ pbias,
                                                unsigned* __restrict__ Mp,
                                                u16* __restrict__ Zn) {
    __shared__ uint4 Ls[512];   // 8KB, used only by the mask branch
    __shared__ float rs[4], rss[4];
    const int bid = blockIdx.x, t = threadIdx.x;
    if (bid < 3072) {            // qkv cast + row permute: rows = [V|Q|K], each h*64+t
        int i = bid * 256 + t;
        int orow = i >> 8, cc = i & 255;
        int region = orow >> 10, rem = orow & 1023, h = rem >> 6, tt = rem & 63;
        int srow = h * 192 + region * 64 + tt;
        float4 v = ((const float4*)qkv_w)[srow * 256 + cc];
        ushort4 o;
        o.x = f2bf(v.x); o.y = f2bf(v.y); o.z = f2bf(v.z); o.w = f2bf(v.w);
        ((ushort4*)qkvW)[i] = o;
    } else if (bid < 4096) {     // o_w cast
        int i = (bid - 3072) * 256 + t;
        float4 v = ((const float4*)o_w)[i];
        ushort4 o;
        o.x = f2bf(v.x); o.y = f2bf(v.y); o.z = f2bf(v.z); o.w = f2bf(v.w);
        ((ushort4*)oW)[i] = o;
    } else if (bid < 8192) {     // p1_w cast
        int i = (bid - 4096) * 256 + t;
        float4 v = ((const float4*)p1_w)[i];
        ushort4 o;
        o.x = f2bf(v.x); o.y = f2bf(v.y); o.z = f2bf(v.z); o.w = f2bf(v.w);
        ((ushort4*)p1W)[i] = o;
    } else if (bid < 12288) {    // p2_w cast
        int i = (bid - 8192) * 256 + t;
        float4 v = ((const float4*)p2_w)[i];
        ushort4 o;
        o.x = f2bf(v.x); o.y = f2bf(v.y); o.z = f2bf(v.z); o.w = f2bf(v.w);
        ((ushort4*)p2W)[i] = o;
    } else if (bid < 16384) {    // mask pack: LDS-transposed, dense in and out
        // tile = one b, one mt (32 m), 64 n. layout out: [b][mt][c][n][hi] uint4
        const int idx = bid - 12288;
        const int bb = idx >> 11, r2 = idx & 2047;
        const int mt = r2 >> 5, nt = r2 & 31;
        const int n0 = nt * 64;
        // read: 2 consecutive float4 (8 m) per array per thread, coalesced
        const int n = t >> 2;
        const int mq0 = (t & 3) * 2;
        const size_t fbase = (size_t)bb * 1048576 + (size_t)(n0 + n) * 512 + mt * 8 + mq0;
        const float4 a0 = ((const float4*)nm)[fbase];
        const float4 a1 = ((const float4*)nm)[fbase + 1];
        const float4 b0 = ((const float4*)pm)[fbase];
        const float4 b1 = ((const float4*)pm)[fbase + 1];
        uint4 o0, o1;
        o0.x = ((unsigned)f2bf(b0.x) << 16) | f2bf(a0.x * 1.4426950f);
        o0.y = ((unsigned)f2bf(b0.y) << 16) | f2bf(a0.y * 1.4426950f);
        o0.z = ((unsigned)f2bf(b0.z) << 16) | f2bf(a0.z * 1.4426950f);
        o0.w = ((unsigned)f2bf(b0.w) << 16) | f2bf(a0.w * 1.4426950f);
        o1.x = ((unsigned)f2bf(b1.x) << 16) | f2bf(a1.x * 1.4426950f);
        o1.y = ((unsigned)f2bf(b1.y) << 16) | f2bf(a1.y * 1.4426950f);
        o1.z = ((unsigned)f2bf(b1.z) << 16) | f2bf(a1.z * 1.4426950f);
        o1.w = ((unsigned)f2bf(b1.w) << 16) | f2bf(a1.w * 1.4426950f);
        // slot: m5 = 8c + 4hi + {0..3};  mq0 even -> (c=mq0>>1, hi=0), mq0+1 -> hi=1
        const int c = mq0 >> 1;
        Ls[c * 128 + n * 2 + 0] = o0;
        Ls[c * 128 + n * 2 + 1] = o1;
        __syncthreads();
        // write: per c, 128 consecutive uint4 (2KB) fully coalesced
        const int wc = t >> 6, j = t & 63;
        const size_t obase = (((size_t)(bb * 64 + mt) * 4) + wc) * 4096 + (size_t)n0 * 2;
        ((uint4*)Mp)[obase + j] = Ls[wc * 128 + j];
        ((uint4*)Mp)[obase + 64 + j] = Ls[wc * 128 + 64 + j];
    } else if (bid < 20480) {    // LN1: one row per block
        const int row = bid - 16384;
        const float4 v = ((const float4*)(Z + (size_t)row * 1024))[t];
        float s = v.x + v.y + v.z + v.w;
        float ss = v.x * v.x + v.y * v.y + v.z * v.z + v.w * v.w;
#pragma unroll
        for (int o = 1; o < 64; o <<= 1) {
            s += __shfl_xor(s, o);
            ss += __shfl_xor(ss, o);
        }
        const int wave = t >> 6, lane = t & 63;
        if (lane == 0) { rs[wave] = s; rss[wave] = ss; }
        __syncthreads();
        const float tot = rs[0] + rs[1] + rs[2] + rs[3];
        const float totss = rss[0] + rss[1] + rss[2] + rss[3];
        const float mu = tot * (1.0f / 1024.0f);
        const float var = totss * (1.0f / 1024.0f) - mu * mu;
        const float rstd = rsqrtf(var + 1e-5f);
        const float4 g4 = ((const float4*)ln1_g)[t];
        const float4 b4 = ((const float4*)ln1_b)[t];
        ushort4 o;
        o.x = f2bf((v.x - mu) * rstd * g4.x + b4.x);
        o.y = f2bf((v.y - mu) * rstd * g4.y + b4.y);
        o.z = f2bf((v.z - mu) * rstd * g4.z + b4.z);
        o.w = f2bf((v.w - mu) * rstd * g4.w + b4.w);
        ((ushort4*)(Zn + (size_t)row * 1024))[t] = o;
    } else {                     // qkv bias permute (3072 elements)
#pragma unroll
        for (int k = 0; k < 12; k++) {
            int i = k * 256 + t;
            int region = i >> 10, rem = i & 1023, h = rem >> 6, tt = rem & 63;
            pbias[i] = qkv_b[h * 192 + region * 64 + tt];
        }
    }
}

// ---- fused 2-way combine + residual + LayerNorm ----
__global__ __launch_bounds__(256) void ln2_comb2(const float* __restrict__ p0,
                                                 const float* __restrict__ p1,
                                                 const float* __restrict__ Z,
                                                 const float* __restrict__ gam,
                                                 const float* __restrict__ bet,
                                                 float* __restrict__ Z1,
                                                 u16* __restrict__ y) {
    const int row = blockIdx.x;
    const int t = threadIdx.x;
    const size_t off = (size_t)row * 256 + t;
    const float4 a = ((const float4*)p0)[off];
    const float4 c = ((const float4*)p1)[off];
    const float4 z = ((const float4*)Z)[off];
    float4 v;
    v.x = a.x + c.x + z.x;
    v.y = a.y + c.y + z.y;
    v.z = a.z + c.z + z.z;
    v.w = a.w + c.w + z.w;
    ((float4*)Z1)[off] = v;
    float s = v.x + v.y + v.z + v.w;
    float ss = v.x * v.x + v.y * v.y + v.z * v.z + v.w * v.w;
#pragma unroll
    for (int o = 1; o < 64; o <<= 1) {
        s += __shfl_xor(s, o);
        ss += __shfl_xor(ss, o);
    }
    __shared__ float rs[4], rss[4];
    const int wave = t >> 6, lane = t & 63;
    if (lane == 0) { rs[wave] = s; rss[wave] = ss; }
    __syncthreads();
    const float tot = rs[0] + rs[1] + rs[2] + rs[3];
    const float totss = rss[0] + rss[1] + rss[2] + rss[3];
    const float mu = tot * (1.0f / 1024.0f);
    const float var = totss * (1.0f / 1024.0f) - mu * mu;
    const float rstd = rsqrtf(var + 1e-5f);
    const float4 g4 = ((const float4*)gam)[t];
    const float4 b4 = ((const float4*)bet)[t];
    ushort4 o;
    o.x = f2bf((v.x - mu) * rstd * g4.x + b4.x);
    o.y = f2bf((v.y - mu) * rstd * g4.y + b4.y);
    o.z = f2bf((v.z - mu) * rstd * g4.z + b4.z);
    o.w = f2bf((v.w - mu) * rstd * g4.w + b4.w);
    ((ushort4*)(y + (size_t)row * 1024))[t] = o;
}

// ---- final combine: out = p0 + p1 + bias + Z1 ----
__global__ __launch_bounds__(256) void out_comb(const float* __restrict__ p0,
                                                const float* __restrict__ p1,
                                                const float* __restrict__ bias,
                                                const float* __restrict__ Z1,
                                                float* __restrict__ out) {
    int i = blockIdx.x * 256 + threadIdx.x;   // 1048576 float4s
    float4 a = ((const float4*)p0)[i];
    float4 c = ((const float4*)p1)[i];
    float4 z = ((const float4*)Z1)[i];
    float4 b = ((const float4*)bias)[i & 255];
    float4 o;
    o.x = a.x + c.x + z.x + b.x; o.y = a.y + c.y + z.y + b.y;
    o.z = a.z + c.z + z.z + b.z; o.w = a.w + c.w + z.w + b.w;
    ((float4*)out)[i] = o;
}

// ---------------- GEMM v12: counted-vmcnt pipeline (no full drains) ----------------
// C[M,N] = A[M,K-slice] @ Bt[N,K-slice]^T. 128x128 tile, BK=32, 2-deep dbuf.
// Per phase: {vmcnt(4); barrier} (buf ready, other buf's loads stay in flight)
// -> ds_read frags -> {lgkmcnt(0); barrier} (buf free) -> refill -> MFMA.
// EPI 0: +pbias; region: 0 -> f32 Vsc(out0), 1 -> Q bf16(out1), 2 -> K bf16(out2)
// EPI 2: +bias, relu, write bf16 out0
// EPI 4: raw f32 partial -> out0 + z*M*N
template <int EPI>
__global__ __launch_bounds__(256, 3) void gemm_bt(const u16* __restrict__ A,
                                                  const u16* __restrict__ Bt,
                                                  const float* __restrict__ bias,
                                                  void* __restrict__ out0,
                                                  void* __restrict__ out1,
                                                  void* __restrict__ out2,
                                                  int M, int N, int K, int ldk) {
    __shared__ __align__(16) u16 As[2][128 * 32];
    __shared__ __align__(16) u16 Bs[2][128 * 32];
    const int tid = threadIdx.x;
    const int wave = tid >> 6, lane = tid & 63;
    const int lhi = lane >> 4, llo = lane & 15;
    // XCD-chunked block swizzle (nwg_xy is a multiple of 8 for all call sites)
    const int gx = gridDim.x;
    const int bid = blockIdx.y * gx + blockIdx.x;
    const int swz = (bid & 7) * ((gx * gridDim.y) >> 3) + (bid >> 3);
    const int bx = swz % gx, by = swz / gx;
    const int kz = blockIdx.z * K;

    const int arow = wave * 32 + (lane >> 2);
    const int asw = ((lane & 3) ^ ((lane >> 2) & 3)) << 3;  // pre-swizzled source col
    const u16* gA = A + (size_t)(by * 128 + arow) * ldk + kz + asw;
    const u16* gB = Bt + (size_t)(bx * 128 + arow) * ldk + kz + asw;
    u16* lA0 = As[0] + wave * 1024 + lane * 8;
    u16* lA1 = As[1] + wave * 1024 + lane * 8;
    u16* lB0 = Bs[0] + wave * 1024 + lane * 8;
    u16* lB1 = Bs[1] + wave * 1024 + lane * 8;

#define GSTAGE(LA, LB) do { \
        gl_lds16(gA, LA); gl_lds16(gA + 16 * (size_t)ldk, (LA) + 512); \
        gl_lds16(gB, LB); gl_lds16(gB + 16 * (size_t)ldk, (LB) + 512); \
        gA += 32; gB += 32; } while (0)

    const int wr = wave >> 1, wc = wave & 1;
    const f32x4 zero = {0.f, 0.f, 0.f, 0.f};
    f32x4 acc[4][4];
#pragma unroll
    for (int i = 0; i < 4; i++)
#pragma unroll
        for (int j = 0; j < 4; j++) acc[i][j] = zero;

    // sw4 read offsets: row r, global chunk lhi lives at LDS chunk (lhi ^ (r&3))
    // Phase: ready-wait (counted) -> barrier -> reads -> lgkm0 -> barrier (free)
    // -> conditional refill of the just-freed buffer -> MFMA cluster.
#define GPHASE(AB, BB, DO_REFILL, LA, LB, LASTWAIT) do { \
        if (LASTWAIT) asm volatile("s_waitcnt vmcnt(0)" ::: "memory"); \
        else          asm volatile("s_waitcnt vmcnt(4)" ::: "memory"); \
        __builtin_amdgcn_s_barrier(); \
        bf16x8 af[4], bfr[4]; \
        _Pragma("unroll") \
        for (int i = 0; i < 4; i++) { \
            const int r = wr * 64 + i * 16 + llo; \
            af[i] = *(const bf16x8*)((AB) + r * 32 + (((lhi ^ r) & 3) << 3)); \
        } \
        _Pragma("unroll") \
        for (int j = 0; j < 4; j++) { \
            const int r = wc * 64 + j * 16 + llo; \
            bfr[j] = *(const bf16x8*)((BB) + r * 32 + (((lhi ^ r) & 3) << 3)); \
        } \
        asm volatile("s_waitcnt lgkmcnt(0)" ::: "memory"); \
        __builtin_amdgcn_sched_barrier(0); \
        __builtin_amdgcn_s_barrier(); \
        if (DO_REFILL) GSTAGE(LA, LB); \
        __builtin_amdgcn_s_setprio(1); \
        _Pragma("unroll") \
        for (int i = 0; i < 4; i++) \
            _Pragma("unroll") \
            for (int j = 0; j < 4; j++) \
                acc[i][j] = __builtin_amdgcn_mfma_f32_16x16x32_bf16(af[i], bfr[j], acc[i][j], 0, 0, 0); \
        __builtin_amdgcn_s_setprio(0); \
        } while (0)

    // prologue: 2-deep prefetch
    GSTAGE(lA0, lB0);
    GSTAGE(lA1, lB1);
    for (int k0 = 0; k0 < K; k0 += 64) {
        const bool r0 = (k0 + 64 < K);   // refill buf0 with k0+64
        const bool r1 = (k0 + 96 < K);   // refill buf1 with k0+96
        GPHASE(As[0], Bs[0], r0, lA0, lB0, false);
        GPHASE(As[1], Bs[1], r1, lA1, lB1, !r0);
    }
#undef GPHASE
#undef GSTAGE

    const int rbase = by * 128 + wr * 64 + lhi * 4;
    const int cbase = bx * 128 + wc * 64 + llo;
    float* pout = nullptr;
    if constexpr (EPI == 4) {
        pout = (float*)out0 + (size_t)blockIdx.z * M * N;
    }
#pragma unroll
    for (int i = 0; i < 4; i++) {
#pragma unroll
        for (int j = 0; j < 4; j++) {
#pragma unroll
            for (int r = 0; r < 4; r++) {
                const int row = rbase + i * 16 + r;
                const int col = cbase + j * 16;
                float v = acc[i][j][r];
                if constexpr (EPI == 0) {
                    v += bias[col];
                    const int region = col >> 10;   // uniform per block
                    const int c = col & 1023;       // h*64 + t
                    const int b = row >> 11, n = row & 2047;
                    if (region == 0) {
                        ((float*)out0)[(size_t)row * 1024 + c] = v;  // Vsc f32
                    } else {
                        const int h = c >> 6, t = c & 63;
                        u16* dst = (region == 1) ? (u16*)out1 : (u16*)out2;
                        dst[(((size_t)(b * 16 + h)) * 2048 + n) * 64 + t] = f2bf(v);
                    }
                } else if constexpr (EPI == 2) {
                    v += bias[col];
                    v = v > 0.f ? v : 0.f;
                    ((u16*)out0)[(size_t)row * N + col] = f2bf(v);
                } else {
                    pout[(size_t)row * N + col] = v;
                }
            }
        }
    }
}

// ---------------- V transpose: Vsc f32 [B*N][1024] -> Vt bf16 [BH][64][2048] --
// m-columns written in PV k-order (pg permutation within each 32-m block).
__global__ __launch_bounds__(256) void vtrans(const float* __restrict__ Vsc,
                                              u16* __restrict__ Vt) {
    __shared__ u16 Ts[64 * 72];
    const int nt = blockIdx.x;  // n-tile (0..31)
    const int bh = blockIdx.y;  // 0..31
    const int b = bh >> 4, h = bh & 15;
    const int t = threadIdx.x;
    const int n0 = nt * 64;
    const int nr = t >> 2;
    const int dq = (t & 3) * 16;
    const float* src = Vsc + ((size_t)(b * 2048 + n0 + nr)) * 1024 + h * 64 + dq;
    float4 v0 = ((const float4*)src)[0];
    float4 v1 = ((const float4*)src)[1];
    float4 v2 = ((const float4*)src)[2];
    float4 v3 = ((const float4*)src)[3];
    u16* c0 = Ts + nr;
    c0[(dq + 0) * 72]  = f2bf(v0.x); c0[(dq + 1) * 72]  = f2bf(v0.y);
    c0[(dq + 2) * 72]  = f2bf(v0.z); c0[(dq + 3) * 72]  = f2bf(v0.w);
    c0[(dq + 4) * 72]  = f2bf(v1.x); c0[(dq + 5) * 72]  = f2bf(v1.y);
    c0[(dq + 6) * 72]  = f2bf(v1.z); c0[(dq + 7) * 72]  = f2bf(v1.w);
    c0[(dq + 8) * 72]  = f2bf(v2.x); c0[(dq + 9) * 72]  = f2bf(v2.y);
    c0[(dq + 10) * 72] = f2bf(v2.z); c0[(dq + 11) * 72] = f2bf(v2.w);
    c0[(dq + 12) * 72] = f2bf(v3.x); c0[(dq + 13) * 72] = f2bf(v3.y);
    c0[(dq + 14) * 72] = f2bf(v3.z); c0[(dq + 15) * 72] = f2bf(v3.w);
    __syncthreads();
    const int d = t >> 2, n8 = (t & 3) * 16;
    u16* dstrow = Vt + ((size_t)bh * 64 + d) * 2048 + n0;
#pragma unroll
    for (int w = 0; w < 4; w++) {
        const int gi = (n8 >> 2) + w;          // m-group id within 64-tile
        const int g5 = gi & 7, blk = gi >> 3;
        const int pg = (g5 & 4) | ((g5 & 1) << 1) | ((g5 >> 1) & 1);
        *(uint2*)(dstrow + blk * 32 + pg * 4) = *(const uint2*)(Ts + d * 72 + n8 + w * 4);
    }
}

// ---------------- fused flash-style attention v8 (proven 70us config) ----------------
__global__ __launch_bounds__(256, 4) void attn_fused8(const u16* __restrict__ Qg,
                                                      const u16* __restrict__ Kg,
                                                      const u16* __restrict__ Vtg,
                                                      const unsigned* __restrict__ Mp,
                                                      u16* __restrict__ attnL) {
    __shared__ __align__(16) u16 Ks[2][64 * 64];
    __shared__ __align__(16) u16 Vs[2][64 * 64];
    __shared__ float lsh[2][32], lsh2[2][32];
    const int tid = threadIdx.x, wave = tid >> 6, lane = tid & 63;
    const int qh = wave & 1, wm = wave >> 1;       // q-half, m-split
    const int hi = lane >> 5, l31 = lane & 31;
    // XCD-grouped block decode: 16 heads of a (b,qt) group on one XCD
    const int pid = blockIdx.x;
    const int seq = pid >> 3;
    const int hh = seq & 15;
    const int g = (pid & 7) + (seq >> 4) * 8;
    const int b = g >> 5, qt = g & 31;
    const int bh = b * 16 + hh;
    const int q0 = qt * 64;

    // loop-carried staging pointers
    const int l3 = lane >> 3, l7 = lane & 7;
    const int swcol = (l7 ^ l3) << 3;
    const int srow = wave * 16 + l3;
    const u16* kp = Kg + ((size_t)bh * 2048 + srow) * 64 + swcol;
    const u16* vp = Vtg + ((size_t)bh * 64 + srow) * 2048 + swcol;
    u16* lKa = Ks[0] + wave * 1024 + lane * 8;
    u16* lKb = Ks[1] + wave * 1024 + lane * 8;
    u16* lVa = Vs[0] + wave * 1024 + lane * 8;
    u16* lVb = Vs[1] + wave * 1024 + lane * 8;

#define STAGE(LK, LV) do { \
        gl_lds16(kp, LK); gl_lds16(kp + 512, (LK) + 512); \
        gl_lds16(vp, LV); gl_lds16(vp + 16384, (LV) + 512); \
        kp += 4096; vp += 64; } while (0)

    // prologue: stage tile 0, Q fragments to registers
    STAGE(lKa, lVa);
    const int qrow = q0 + qh * 32 + l31;
    const u16* qptr = Qg + ((size_t)bh * 2048 + qrow) * 64 + hi * 8;
    bf16x8 qf[4];
#pragma unroll
    for (int ks = 0; ks < 4; ks++) qf[ks] = *(const bf16x8*)(qptr + ks * 16);

    // coalesced mask base: [b][mt][c][n][hi] (uint4 units), mt = 2t + wm
    const uint4* mp = (const uint4*)Mp + (size_t)(b * 64 + wm) * 16384
                                       + (size_t)qrow * 2 + hi;

    const f32x16 z16 = {0.f,0.f,0.f,0.f,0.f,0.f,0.f,0.f,0.f,0.f,0.f,0.f,0.f,0.f,0.f,0.f};
    f32x16 accO[2];
    accO[0] = z16; accO[1] = z16;
    f32x2 lsv = {0.f, 0.f};
    const float CS = 0.125f * 1.4426950f;
    const f32x2 csv = {CS, CS};
    __syncthreads();

#define QUAD(M, q) { \
        f32x2 nm0 = {uaf(M.x << 16), uaf(M.y << 16)}; \
        f32x2 nm1 = {uaf(M.z << 16), uaf(M.w << 16)}; \
        const f32x2 sa = {sacc[q], sacc[q + 1]}; \
        const f32x2 sb = {sacc[q + 2], sacc[q + 3]}; \
        nm0 += sa * csv; nm1 += sb * csv; \
        f32x2 e0 = {__builtin_amdgcn_exp2f(nm0.x), __builtin_amdgcn_exp2f(nm0.y)}; \
        f32x2 e1 = {__builtin_amdgcn_exp2f(nm1.x), __builtin_amdgcn_exp2f(nm1.y)}; \
        lsv += e0; lsv += e1; \
        const f32x2 pm0 = {uaf(M.x & 0xFFFF0000u), uaf(M.y & 0xFFFF0000u)}; \
        const f32x2 pm1 = {uaf(M.z & 0xFFFF0000u), uaf(M.w & 0xFFFF0000u)}; \
        e0 *= pm0; e1 *= pm1; \
        wpk[(q) / 2] = cvtpk_bf16(e0.x, e0.y); \
        wpk[(q) / 2 + 1] = cvtpk_bf16(e1.x, e1.y); }

    // masks for CURRENT tile load first (4 VMEM), then next-tile STAGE (8 VMEM):
    // the softmax's wait on masks leaves the stage loads in flight; the barrier
    // at iter end drains the stage.
#define ITER(KSB, VSB, LK, LV, DO_STAGE) do { \
        const uint4 M0 = mp[0], M1 = mp[4096], M2 = mp[8192], M3 = mp[12288]; \
        mp += 32768; \
        if (DO_STAGE) STAGE(LK, LV); \
        f32x16 sacc = z16; \
        __builtin_amdgcn_s_setprio(1); \
        _Pragma("unroll") \
        for (int ks = 0; ks < 4; ks++) { \
            const bf16x8 kf = *(const bf16x8*)((KSB) + sw8(wm * 32 + l31, ks * 2 + hi)); \
            sacc = __builtin_amdgcn_mfma_f32_32x32x16_bf16(kf, qf[ks], sacc, 0, 0, 0); \
        } \
        __builtin_amdgcn_s_setprio(0); \
        unsigned wpk[8]; \
        QUAD(M0, 0) QUAD(M1, 4) QUAD(M2, 8) QUAD(M3, 12) \
        const u32x4 fa0v = {wpk[0], wpk[1], wpk[2], wpk[3]}; \
        const u32x4 fa1v = {wpk[4], wpk[5], wpk[6], wpk[7]}; \
        const bf16x8 pa0 = __builtin_bit_cast(bf16x8, fa0v); \
        const bf16x8 pa1 = __builtin_bit_cast(bf16x8, fa1v); \
        __builtin_amdgcn_s_setprio(1); \
        _Pragma("unroll") \
        for (int dh = 0; dh < 2; dh++) { \
            const bf16x8 vf0 = *(const bf16x8*)((VSB) + sw8(dh * 32 + l31, wm * 4 + hi)); \
            accO[dh] = __builtin_amdgcn_mfma_f32_32x32x16_bf16(pa0, vf0, accO[dh], 0, 0, 0); \
            const bf16x8 vf1 = *(const bf16x8*)((VSB) + sw8(dh * 32 + l31, wm * 4 + 2 + hi)); \
            accO[dh] = __builtin_amdgcn_mfma_f32_32x32x16_bf16(pa1, vf1, accO[dh], 0, 0, 0); \
        } \
        __builtin_amdgcn_s_setprio(0); \
        __syncthreads(); } while (0)

    for (int tt = 0; tt < 16; tt++) {
        ITER(Ks[0], Vs[0], lKb, lVb, true);          // even tile 2tt; stage 2tt+1
        ITER(Ks[1], Vs[1], lKa, lVa, (tt < 15));     // odd tile 2tt+1; stage 2tt+2
    }
#undef ITER
#undef QUAD
#undef STAGE

    // combine the wm pair (same qh): conflict-free XOR-swizzled LDS buffer
    const float lsum = lsv.x + lsv.y;
    const float lsum2 = lsum + __shfl_xor(lsum, 32);
    float* cb = (float*)&Ks[0][0];   // 16 KB: 128 slots x 32 floats, swizzled
    const int slot = qh * 64 + lane;
    const int s7 = slot & 7;
    if (wm == 1) {
        float* dst = cb + (size_t)slot * 32;
#pragma unroll
        for (int dh = 0; dh < 2; dh++)
#pragma unroll
            for (int c = 0; c < 4; c++) {
                const f32x4 v = {accO[dh][c * 4 + 0], accO[dh][c * 4 + 1],
                                 accO[dh][c * 4 + 2], accO[dh][c * 4 + 3]};
                *(f32x4*)(dst + (((dh * 4 + c) ^ s7) << 2)) = v;
            }
        if (lane < 32) lsh[qh][lane] = lsum2;
    }
    __syncthreads();
    if (wm == 0) {
        const float* src = cb + (size_t)slot * 32;
        const float lt = lsum2 + lsh[qh][l31];
#pragma unroll
        for (int dh = 0; dh < 2; dh++)
#pragma unroll
            for (int c = 0; c < 4; c++) {
                const f32x4 v = *(const f32x4*)(src + (((dh * 4 + c) ^ s7) << 2));
                accO[dh][c * 4 + 0] += v.x;
                accO[dh][c * 4 + 1] += v.y;
                accO[dh][c * 4 + 2] += v.z;
                accO[dh][c * 4 + 3] += v.w;
            }
        if (lane < 32) lsh2[qh][lane] = 1.0f / lt;
    }
    __syncthreads();
    if (wm == 0) {
#pragma unroll
        for (int r = 0; r < 16; r++) {
            const int ql = (r & 3) + 8 * (r >> 2) + 4 * hi;
            const float linv = lsh2[qh][ql];
            const int qg = q0 + qh * 32 + ql;
#pragma unroll
            for (int dh = 0; dh < 2; dh++) {
                float v = accO[dh][r] * linv;
                v = v >= 0.f ? v : 0.01f * v;
                attnL[((size_t)b * 2048 + qg) * 1024 + hh * 64 + dh * 32 + l31] = f2bf(v);
            }
        }
    }
}

// ---------------- launcher ----------------
extern "C" void kernel_launch(void* const* d_in, const int* in_sizes, int n_in,
                              void* d_out, int out_size, void* d_ws, size_t ws_size,
                              hipStream_t stream) {
    const float* Z     = (const float*)d_in[0];
    const float* nmask = (const float*)d_in[1];
    const float* pmask = (const float*)d_in[2];
    const float* ln1_g = (const float*)d_in[3];
    const float* ln1_b = (const float*)d_in[4];
    const float* qkv_w = (const float*)d_in[5];
    const float* qkv_b = (const float*)d_in[6];
    const float* o_w   = (const float*)d_in[7];
    const float* ln2_g = (const float*)d_in[8];
    const float* ln2_b = (const float*)d_in[9];
    const float* p1_w  = (const float*)d_in[10];
    const float* p1_b  = (const float*)d_in[11];
    const float* p2_w  = (const float*)d_in[12];
    const float* p2_b  = (const float*)d_in[13];
    float* out = (float*)d_out;

    char* w = (char*)d_ws;
    auto take = [&](size_t bytes) -> char* {
        char* p = w;
        w += (bytes + 255) & ~(size_t)255;
        return p;
    };
    u16* qkvW   = (u16*)take((size_t)3072 * 1024 * 2);
    u16* oW     = (u16*)take((size_t)1024 * 1024 * 2);
    u16* p1W    = (u16*)take((size_t)4096 * 1024 * 2);
    u16* p2W    = (u16*)take((size_t)1024 * 4096 * 2);
    u16* Zn     = (u16*)take((size_t)4096 * 1024 * 2);   // reused for Zn2
    u16* Qb     = (u16*)take((size_t)32 * 2048 * 64 * 2);
    u16* Kb     = (u16*)take((size_t)32 * 2048 * 64 * 2);
    u16* Vt     = (u16*)take((size_t)32 * 64 * 2048 * 2);
    u16* attnL  = (u16*)take((size_t)4096 * 1024 * 2);
    float* Z1   = (float*)take((size_t)4096 * 1024 * 4);
    u16* hbuf   = (u16*)take((size_t)4096 * 4096 * 2);   // 33.55 MB
    unsigned* Mp = (unsigned*)take((size_t)2 * 2048 * 2048 * 4);  // 33.55 MB
    float* pbias = (float*)take((size_t)3072 * 4);
    float* Vsc    = (float*)hbuf;          // alias: dead before hbuf written
    float* part01 = (float*)Mp;            // alias: Mp dead after attention
    float* part23 = (float*)hbuf;          // alias: hbuf dead during o-proj

    // merged prep (casts + bias permute + dense mask transpose-pack + LN1)
    prep_all<<<dim3(20481), 256, 0, stream>>>(qkv_w, o_w, p1_w, p2_w, qkv_b, nmask, pmask,
                                              Z, ln1_g, ln1_b,
                                              qkvW, oW, p1W, p2W, pbias, Mp, Zn);
    // QKV projection: V -> f32 scratch (dense), Q/K -> bf16 [BH][N][64]
    gemm_bt<0><<<dim3(24, 32), 256, 0, stream>>>(Zn, qkvW, pbias, Vsc, Qb, Kb, 4096, 3072, 1024, 1024);
    // V transpose -> Vt [BH][64][2048] (PV k-order columns, dense writes)
    vtrans<<<dim3(32, 32), 256, 0, stream>>>(Vsc, Vt);
    // attention (4 blocks/CU, in-register softmax)
    attn_fused8<<<dim3(1024), 256, 0, stream>>>(Qb, Kb, Vt, Mp, attnL);
    // o-projection, split-K=2 -> f32 partials in Mp (2 x 16.8 MB)
    gemm_bt<4><<<dim3(8, 32, 2), 256, 0, stream>>>(attnL, oW, nullptr, part01, nullptr, nullptr,
                                                   4096, 1024, 512, 1024);
    // 2-way combine + residual + LN2 (writes Z1 and Zn)
    ln2_comb2<<<dim3(4096), 256, 0, stream>>>(part01, part01 + (size_t)4096 * 1024,
                                              Z, ln2_g, ln2_b, Z1, Zn);
    // MLP up + relu -> hbuf (bf16)
    gemm_bt<2><<<dim3(32, 32), 256, 0, stream>>>(Zn, p1W, p1_b, hbuf, nullptr, nullptr,
                                                 4096, 4096, 1024, 1024);
    // MLP down, split-K=2 -> f32 partials in Mp
    gemm_bt<4><<<dim3(8, 32, 2), 256, 0, stream>>>(hbuf, p2W, nullptr, part01, nullptr, nullptr,
                                                   4096, 1024, 2048, 4096);
    // final combine -> out
    out_comb<<<dim3(4096), 256, 0, stream>>>(part01, part01 + (size_t)4096 * 1024, p2_b, Z1, out);
}